// Round 1
// baseline (1052.820 us; speedup 1.0000x reference)
//
#include <hip/hip_runtime.h>
#include <hip/hip_bf16.h>
#include <cstdint>
#include <cstddef>

typedef unsigned short u16;
typedef __attribute__((ext_vector_type(8))) short short8;   // 8 bf16 = 4 VGPRs (MFMA A/B frag)
typedef __attribute__((ext_vector_type(4))) float f32x4;    // MFMA C/D frag

__device__ __forceinline__ u16 f2bf(float f) {
    union { float f; uint32_t u; } v; v.f = f;
    uint32_t u = v.u;
    return (u16)((u + 0x7fffu + ((u >> 16) & 1u)) >> 16);   // RNE
}
__device__ __forceinline__ float bf2f(u16 u) {
    union { uint32_t u; float f; } v; v.u = ((uint32_t)u) << 16;
    return v.f;
}

// ---------------- cast fp32 -> bf16 (vectorized) ----------------
__global__ __launch_bounds__(256) void cast_f32_bf16(const float* __restrict__ in,
                                                     u16* __restrict__ out, int n) {
    int i = (blockIdx.x * 256 + threadIdx.x) * 4;
    if (i >= n) return;
    float4 v = *(const float4*)(in + i);
    ushort4 r;
    r.x = f2bf(v.x); r.y = f2bf(v.y); r.z = f2bf(v.z); r.w = f2bf(v.w);
    *(ushort4*)(out + i) = r;
}

// ---------------- W (K,N) fp32 -> Wt (N,K) bf16, 64x64 LDS tiles ----------------
__global__ __launch_bounds__(256) void transpose_cast(const float* __restrict__ W,
                                                      u16* __restrict__ Wt, int K, int N) {
    __shared__ u16 tile[64][72];
    int kt = blockIdx.x * 64, nt = blockIdx.y * 64;
    int t = threadIdx.x;
#pragma unroll
    for (int i = 0; i < 16; i++) {
        int idx = t + i * 256; int kl = idx >> 6, nl = idx & 63;
        tile[kl][nl] = f2bf(W[(size_t)(kt + kl) * N + nt + nl]);
    }
    __syncthreads();
#pragma unroll
    for (int i = 0; i < 16; i++) {
        int idx = t + i * 256; int nl = idx >> 6, kl = idx & 63;
        Wt[(size_t)(nt + nl) * K + kt + kl] = tile[kl][nl];
    }
}

// ---------------- bf16 GEMM: C(M,N) = A(M,K) @ Bt(N,K)^T ----------------
// 128x128 tile, BK=32, 4 waves in 2x2 (each 64x64), mfma 16x16x32 bf16.
template <int OUTF32>
__global__ __launch_bounds__(256) void gemm_bt(const u16* __restrict__ A,
                                               const u16* __restrict__ Bt,
                                               void* __restrict__ Cout,
                                               int M, int N, int K) {
    __shared__ __align__(16) u16 Al[128 * 40];   // rows padded to 40 elems (80B stride)
    __shared__ __align__(16) u16 Bl[128 * 40];
    int m0 = blockIdx.x * 128, n0 = blockIdx.y * 128;
    int t = threadIdx.x;
    int w = t >> 6, l = t & 63;
    int lm = l & 15, lq = l >> 4;
    int wm = (w >> 1) * 64, wn = (w & 1) * 64;
    f32x4 acc[4][4] = {};

    for (int k0 = 0; k0 < K; k0 += 32) {
#pragma unroll
        for (int c = 0; c < 2; c++) {
            int idx = t + c * 256;          // 0..511 -> 128 rows x 4 chunks
            int row = idx >> 2, kq = idx & 3;
            short8 av = *(const short8*)(A + (size_t)(m0 + row) * K + k0 + kq * 8);
            *(short8*)(Al + row * 40 + kq * 8) = av;
            int brow = n0 + row; if (brow >= N) brow = N - 1;   // clamp (partial-N tiles)
            short8 bv = *(const short8*)(Bt + (size_t)brow * K + k0 + kq * 8);
            *(short8*)(Bl + row * 40 + kq * 8) = bv;
        }
        __syncthreads();
        short8 af[4], bfr[4];
#pragma unroll
        for (int mt = 0; mt < 4; mt++)
            af[mt] = *(const short8*)(Al + (wm + mt * 16 + lm) * 40 + lq * 8);
#pragma unroll
        for (int nt = 0; nt < 4; nt++)
            bfr[nt] = *(const short8*)(Bl + (wn + nt * 16 + lm) * 40 + lq * 8);
#pragma unroll
        for (int mt = 0; mt < 4; mt++)
#pragma unroll
            for (int nt = 0; nt < 4; nt++)
                acc[mt][nt] = __builtin_amdgcn_mfma_f32_16x16x32_bf16(af[mt], bfr[nt], acc[mt][nt], 0, 0, 0);
        __syncthreads();
    }
    // epilogue: C layout col=lane&15, row=(lane>>4)*4+reg
#pragma unroll
    for (int mt = 0; mt < 4; mt++) {
#pragma unroll
        for (int nt = 0; nt < 4; nt++) {
            int col = n0 + wn + nt * 16 + lm;
            if (col < N) {
#pragma unroll
                for (int r = 0; r < 4; r++) {
                    int row = m0 + wm + mt * 16 + lq * 4 + r;
                    if (OUTF32) ((float*)Cout)[(size_t)row * N + col] = acc[mt][nt][r];
                    else        ((u16*)Cout)[(size_t)row * N + col] = f2bf(acc[mt][nt][r]);
                }
            }
        }
    }
}

// ---------------- RoPE in-place on (rows, nheads*64) bf16 ----------------
__global__ __launch_bounds__(256) void rope_kernel(u16* __restrict__ x, int rows,
                                                   int nheads, int Smask) {
    int i = blockIdx.x * 256 + threadIdx.x;
    int total = rows * nheads * 32;
    if (i >= total) return;
    int j = i & 31;
    int h = (i >> 5) % nheads;
    int row = i / (32 * nheads);
    int pos = row & Smask;                       // pos = s (S power of two)
    // inv_freq = 10000^(-j/32) = 2^(-j*log2(10000)/32)
    float f = exp2f((float)j * -0.4152410118609828f);
    float ang = (float)pos * f;
    float c = cosf(ang), s = sinf(ang);
    u16* p = x + (size_t)row * (nheads * 64) + h * 64 + j;
    float x1 = bf2f(p[0]), x2 = bf2f(p[32]);
    p[0]  = f2bf(x1 * c - x2 * s);
    p[32] = f2bf(x2 * c + x1 * s);
}

// ---------------- V slice of kv -> v_t (B,H,128,S) bf16 ----------------
__global__ __launch_bounds__(256) void transpose_v(const u16* __restrict__ kv,
                                                   u16* __restrict__ vt, int S) {
    __shared__ u16 tile[64][72];
    int bh = blockIdx.z; int b = bh >> 4, h = bh & 15;
    int s0 = blockIdx.x * 64, d0 = blockIdx.y * 64;
    int t = threadIdx.x;
#pragma unroll
    for (int i = 0; i < 16; i++) {
        int idx = t + i * 256; int sl = idx >> 6, dl = idx & 63;
        tile[sl][dl] = kv[(size_t)(b * S + s0 + sl) * 4096 + 2048 + h * 128 + d0 + dl];
    }
    __syncthreads();
#pragma unroll
    for (int i = 0; i < 16; i++) {
        int idx = t + i * 256; int dl = idx >> 6, sl = idx & 63;
        vt[((size_t)(bh * 128 + d0 + dl)) * S + s0 + sl] = tile[sl][dl];
    }
}

// ---------------- Flash MLA attention ----------------
// grid: (S/64 q-tiles, B*H). 256 thr = 4 waves, wave w owns q rows q0+16w..+15.
// Qfull = [q_c(h,128) | q_r(h,64)] (192), Kfull = [k_c(h,128) | k_r(64)], V 128.
__global__ __launch_bounds__(256) void mla_attn(const u16* __restrict__ qc,
                                                const u16* __restrict__ qr,
                                                const u16* __restrict__ kvbuf,
                                                const u16* __restrict__ kr,
                                                const u16* __restrict__ vt,
                                                u16* __restrict__ out, int S) {
    __shared__ __align__(16) u16 Plds[4][16 * 72];   // per-wave P tile, 144B row stride
    const float scale = 0.07216878364870323f;        // 1/sqrt(192)
    int bh = blockIdx.y; int b = bh >> 4, h = bh & 15;
    int q0 = blockIdx.x * 64;
    int t = threadIdx.x, w = t >> 6, l = t & 63;
    int lm = l & 15, lq = l >> 4;
    int qrow = q0 + w * 16;

    // Q A-frags in registers: A[m=lane&15][k=lq*8+j]
    short8 aq[6];
    {
        const u16* qc_row = qc + (size_t)(b * S + qrow + lm) * 2048 + h * 128;
#pragma unroll
        for (int ks = 0; ks < 4; ks++) aq[ks] = *(const short8*)(qc_row + ks * 32 + lq * 8);
        const u16* qr_row = qr + (size_t)(b * S + qrow + lm) * 1024 + h * 64;
#pragma unroll
        for (int ks = 0; ks < 2; ks++) aq[4 + ks] = *(const short8*)(qr_row + ks * 32 + lq * 8);
    }

    f32x4 o[8] = {};
    float m_r[4], l_r[4];
#pragma unroll
    for (int r = 0; r < 4; r++) { m_r[r] = -INFINITY; l_r[r] = 0.f; }

    int ntiles = q0 / 64 + 1;
    for (int kt = 0; kt < ntiles; kt++) {
        int kbase = kt * 64;
        f32x4 acc[4] = {};
        const u16* kc_base = kvbuf + (size_t)(b * S + kbase + lm) * 4096 + h * 128;
        const u16* kr_base = kr + (size_t)(b * S + kbase + lm) * 64;
#pragma unroll
        for (int ks = 0; ks < 6; ks++) {
#pragma unroll
            for (int nt = 0; nt < 4; nt++) {
                short8 bk;
                if (ks < 4) bk = *(const short8*)(kc_base + (size_t)nt * 16 * 4096 + ks * 32 + lq * 8);
                else        bk = *(const short8*)(kr_base + (size_t)nt * 16 * 64 + (ks - 4) * 32 + lq * 8);
                acc[nt] = __builtin_amdgcn_mfma_f32_16x16x32_bf16(aq[ks], bk, acc[nt], 0, 0, 0);
            }
        }
        // scale + causal mask (only diagonal tile needs it)
        bool diag = (kt == ntiles - 1);
#pragma unroll
        for (int nt = 0; nt < 4; nt++) {
#pragma unroll
            for (int r = 0; r < 4; r++) {
                float s = acc[nt][r] * scale;
                if (diag) {
                    int ki = kbase + nt * 16 + lm;
                    int qi = q0 + w * 16 + lq * 4 + r;
                    if (ki > qi) s = -INFINITY;
                }
                acc[nt][r] = s;
            }
        }
        // online softmax: rows live in 16-lane groups (same lq), 4 rows per lane via regs
        float mnew[4], alpha[4];
#pragma unroll
        for (int r = 0; r < 4; r++) {
            float mx = fmaxf(fmaxf(acc[0][r], acc[1][r]), fmaxf(acc[2][r], acc[3][r]));
            mx = fmaxf(mx, __shfl_xor(mx, 1));
            mx = fmaxf(mx, __shfl_xor(mx, 2));
            mx = fmaxf(mx, __shfl_xor(mx, 4));
            mx = fmaxf(mx, __shfl_xor(mx, 8));
            mnew[r] = fmaxf(m_r[r], mx);
            alpha[r] = __expf(m_r[r] - mnew[r]);
            m_r[r] = mnew[r];
        }
        u16* pl = Plds[w];
        float rs[4] = {0.f, 0.f, 0.f, 0.f};
#pragma unroll
        for (int nt = 0; nt < 4; nt++) {
#pragma unroll
            for (int r = 0; r < 4; r++) {
                float p = __expf(acc[nt][r] - mnew[r]);
                rs[r] += p;
                pl[(lq * 4 + r) * 72 + nt * 16 + lm] = f2bf(p);
            }
        }
#pragma unroll
        for (int r = 0; r < 4; r++) {
            float x = rs[r];
            x += __shfl_xor(x, 1); x += __shfl_xor(x, 2);
            x += __shfl_xor(x, 4); x += __shfl_xor(x, 8);
            l_r[r] = l_r[r] * alpha[r] + x;
        }
#pragma unroll
        for (int nt = 0; nt < 8; nt++)
#pragma unroll
            for (int r = 0; r < 4; r++) o[nt][r] *= alpha[r];
        // P back as A-frags (same wave wrote it; compiler inserts lgkmcnt waits)
        short8 ap[2];
#pragma unroll
        for (int kp = 0; kp < 2; kp++)
            ap[kp] = *(const short8*)(pl + lm * 72 + kp * 32 + lq * 8);
        // V B-frags from pre-transposed v_t: B[k][n] = V[kbase+k][d], k-contiguous per lane
        const u16* vbase = vt + ((size_t)bh * 128) * S + kbase;
#pragma unroll
        for (int kp = 0; kp < 2; kp++) {
#pragma unroll
            for (int nt = 0; nt < 8; nt++) {
                short8 bv = *(const short8*)(vbase + (size_t)(nt * 16 + lm) * S + kp * 32 + lq * 8);
                o[nt] = __builtin_amdgcn_mfma_f32_16x16x32_bf16(ap[kp], bv, o[nt], 0, 0, 0);
            }
        }
    }
    // epilogue: divide by row sums, store bf16
#pragma unroll
    for (int r = 0; r < 4; r++) l_r[r] = 1.0f / l_r[r];
    u16* orow = out + (size_t)(b * S + qrow) * 2048 + h * 128;
#pragma unroll
    for (int nt = 0; nt < 8; nt++)
#pragma unroll
        for (int r = 0; r < 4; r++)
            orow[(size_t)(lq * 4 + r) * 2048 + nt * 16 + lm] = f2bf(o[nt][r] * l_r[r]);
}

extern "C" void kernel_launch(void* const* d_in, const int* in_sizes, int n_in,
                              void* d_out, int out_size, void* d_ws, size_t ws_size,
                              hipStream_t stream) {
    const int B = 2, S = 2048, D = 2048, H = 16;
    const int M = B * S;                       // 4096
    const float* x    = (const float*)d_in[0];
    const float* Wq   = (const float*)d_in[1];
    const float* Wqr  = (const float*)d_in[2];
    const float* Wkvd = (const float*)d_in[3];
    const float* Wkvu = (const float*)d_in[4];
    const float* Wkr  = (const float*)d_in[5];
    const float* Wo   = (const float*)d_in[6];

    u16* p = (u16*)d_ws;
    u16* xb    = p; p += (size_t)M * D;          // 8.39M
    u16* WqT   = p; p += (size_t)2048 * 2048;
    u16* WqrT  = p; p += (size_t)1024 * 2048;
    u16* WkvdT = p; p += (size_t)512 * 2048;
    u16* WkvuT = p; p += (size_t)4096 * 512;
    u16* WkrT  = p; p += (size_t)64 * 2048;
    u16* WoT   = p; p += (size_t)2048 * 2048;
    u16* q_c   = p; p += (size_t)M * 2048;
    u16* q_r   = p; p += (size_t)M * 1024;
    u16* c_kv  = p; p += (size_t)M * 512;
    u16* k_r   = p; p += (size_t)M * 64;
    u16* kv    = p; p += (size_t)M * 4096;
    u16* v_t   = p; p += (size_t)B * H * 128 * S;
    u16* attn  = p; p += (size_t)M * 2048;

    // 1) casts / transposes
    cast_f32_bf16<<<(M * D) / 4 / 256, 256, 0, stream>>>(x, xb, M * D);
    transpose_cast<<<dim3(32, 32), 256, 0, stream>>>(Wq,   WqT,   2048, 2048);
    transpose_cast<<<dim3(32, 16), 256, 0, stream>>>(Wqr,  WqrT,  2048, 1024);
    transpose_cast<<<dim3(32, 8),  256, 0, stream>>>(Wkvd, WkvdT, 2048, 512);
    transpose_cast<<<dim3(8, 64),  256, 0, stream>>>(Wkvu, WkvuT, 512, 4096);
    transpose_cast<<<dim3(32, 1),  256, 0, stream>>>(Wkr,  WkrT,  2048, 64);
    transpose_cast<<<dim3(32, 32), 256, 0, stream>>>(Wo,   WoT,   2048, 2048);

    // 2) projections
    gemm_bt<0><<<dim3(32, 16), 256, 0, stream>>>(xb, WqT,   q_c,  M, 2048, 2048);
    gemm_bt<0><<<dim3(32, 8),  256, 0, stream>>>(xb, WqrT,  q_r,  M, 1024, 2048);
    gemm_bt<0><<<dim3(32, 4),  256, 0, stream>>>(xb, WkvdT, c_kv, M, 512, 2048);
    gemm_bt<0><<<dim3(32, 1),  256, 0, stream>>>(xb, WkrT,  k_r,  M, 64, 2048);

    // 3) RoPE (in place)
    rope_kernel<<<(M * 16 * 32) / 256, 256, 0, stream>>>(q_r, M, 16, S - 1);
    rope_kernel<<<(M * 32) / 256, 256, 0, stream>>>(k_r, M, 1, S - 1);

    // 4) kv up-projection, V transpose
    gemm_bt<0><<<dim3(32, 32), 256, 0, stream>>>(c_kv, WkvuT, kv, M, 4096, 512);
    transpose_v<<<dim3(32, 2, 32), 256, 0, stream>>>(kv, v_t, S);

    // 5) attention
    mla_attn<<<dim3(32, 32), 256, 0, stream>>>(q_c, q_r, kv, k_r, v_t, attn, S);

    // 6) output projection -> fp32 d_out
    gemm_bt<1><<<dim3(32, 16), 256, 0, stream>>>(attn, WoT, d_out, M, 2048, 2048);
}

// Round 3
// 600.099 us; speedup vs baseline: 1.7544x; 1.7544x over previous
//
#include <hip/hip_runtime.h>
#include <hip/hip_bf16.h>
#include <cstdint>
#include <cstddef>

typedef unsigned short u16;
typedef __attribute__((ext_vector_type(8))) short short8;   // 8 bf16 = 4 VGPRs (MFMA A/B frag)
typedef __attribute__((ext_vector_type(4))) float f32x4;    // MFMA C/D frag

__device__ __forceinline__ u16 f2bf(float f) {
    union { float f; uint32_t u; } v; v.f = f;
    uint32_t u = v.u;
    return (u16)((u + 0x7fffu + ((u >> 16) & 1u)) >> 16);   // RNE
}
__device__ __forceinline__ float bf2f(u16 u) {
    union { uint32_t u; float f; } v; v.u = ((uint32_t)u) << 16;
    return v.f;
}

// ---------------- cast fp32 -> bf16 (vectorized) ----------------
__global__ __launch_bounds__(256) void cast_f32_bf16(const float* __restrict__ in,
                                                     u16* __restrict__ out, int n) {
    int i = (blockIdx.x * 256 + threadIdx.x) * 4;
    if (i >= n) return;
    float4 v = *(const float4*)(in + i);
    ushort4 r;
    r.x = f2bf(v.x); r.y = f2bf(v.y); r.z = f2bf(v.z); r.w = f2bf(v.w);
    *(ushort4*)(out + i) = r;
}

// ---------------- W (K,N) fp32 -> Wt (N,K) bf16, 64x64 LDS tiles ----------------
__global__ __launch_bounds__(256) void transpose_cast(const float* __restrict__ W,
                                                      u16* __restrict__ Wt, int K, int N) {
    __shared__ u16 tile[64][72];
    int kt = blockIdx.x * 64, nt = blockIdx.y * 64;
    int t = threadIdx.x;
#pragma unroll
    for (int i = 0; i < 16; i++) {
        int idx = t + i * 256; int kl = idx >> 6, nl = idx & 63;
        tile[kl][nl] = f2bf(W[(size_t)(kt + kl) * N + nt + nl]);
    }
    __syncthreads();
#pragma unroll
    for (int i = 0; i < 16; i++) {
        int idx = t + i * 256; int nl = idx >> 6, kl = idx & 63;
        Wt[(size_t)(nt + nl) * K + kt + kl] = tile[kl][nl];
    }
}

// ---------------- bf16 GEMM: C(M,N) = A(M,K) @ Bt(N,K)^T ----------------
// 128x128 tile, BK=32, 4 waves in 2x2 (each 64x64), mfma 16x16x32 bf16.
template <int OUTF32>
__global__ __launch_bounds__(256) void gemm_bt(const u16* __restrict__ A,
                                               const u16* __restrict__ Bt,
                                               void* __restrict__ Cout,
                                               int M, int N, int K) {
    __shared__ __align__(16) u16 Al[128 * 40];   // rows padded to 40 elems (80B stride)
    __shared__ __align__(16) u16 Bl[128 * 40];
    int m0 = blockIdx.x * 128, n0 = blockIdx.y * 128;
    int t = threadIdx.x;
    int w = t >> 6, l = t & 63;
    int lm = l & 15, lq = l >> 4;
    int wm = (w >> 1) * 64, wn = (w & 1) * 64;
    f32x4 acc[4][4] = {};

    for (int k0 = 0; k0 < K; k0 += 32) {
#pragma unroll
        for (int c = 0; c < 2; c++) {
            int idx = t + c * 256;          // 0..511 -> 128 rows x 4 chunks
            int row = idx >> 2, kq = idx & 3;
            short8 av = *(const short8*)(A + (size_t)(m0 + row) * K + k0 + kq * 8);
            *(short8*)(Al + row * 40 + kq * 8) = av;
            int brow = n0 + row; if (brow >= N) brow = N - 1;   // clamp (partial-N tiles)
            short8 bv = *(const short8*)(Bt + (size_t)brow * K + k0 + kq * 8);
            *(short8*)(Bl + row * 40 + kq * 8) = bv;
        }
        __syncthreads();
        short8 af[4], bfr[4];
#pragma unroll
        for (int mt = 0; mt < 4; mt++)
            af[mt] = *(const short8*)(Al + (wm + mt * 16 + lm) * 40 + lq * 8);
#pragma unroll
        for (int nt = 0; nt < 4; nt++)
            bfr[nt] = *(const short8*)(Bl + (wn + nt * 16 + lm) * 40 + lq * 8);
#pragma unroll
        for (int mt = 0; mt < 4; mt++)
#pragma unroll
            for (int nt = 0; nt < 4; nt++)
                acc[mt][nt] = __builtin_amdgcn_mfma_f32_16x16x32_bf16(af[mt], bfr[nt], acc[mt][nt], 0, 0, 0);
        __syncthreads();
    }
    // epilogue: C layout col=lane&15, row=(lane>>4)*4+reg
#pragma unroll
    for (int mt = 0; mt < 4; mt++) {
#pragma unroll
        for (int nt = 0; nt < 4; nt++) {
            int col = n0 + wn + nt * 16 + lm;
            if (col < N) {
#pragma unroll
                for (int r = 0; r < 4; r++) {
                    int row = m0 + wm + mt * 16 + lq * 4 + r;
                    if (OUTF32) ((float*)Cout)[(size_t)row * N + col] = acc[mt][nt][r];
                    else        ((u16*)Cout)[(size_t)row * N + col] = f2bf(acc[mt][nt][r]);
                }
            }
        }
    }
}

// ---------------- RoPE in-place on (rows, nheads*64) bf16 ----------------
__global__ __launch_bounds__(256) void rope_kernel(u16* __restrict__ x, int rows,
                                                   int nheads, int Smask) {
    int i = blockIdx.x * 256 + threadIdx.x;
    int total = rows * nheads * 32;
    if (i >= total) return;
    int j = i & 31;
    int h = (i >> 5) % nheads;
    int row = i / (32 * nheads);
    int pos = row & Smask;                       // pos = s (S power of two)
    // inv_freq = 10000^(-j/32) = 2^(-j*log2(10000)/32)
    float f = exp2f((float)j * -0.4152410118609828f);
    float ang = (float)pos * f;
    float c = cosf(ang), s = sinf(ang);
    u16* p = x + (size_t)row * (nheads * 64) + h * 64 + j;
    float x1 = bf2f(p[0]), x2 = bf2f(p[32]);
    p[0]  = f2bf(x1 * c - x2 * s);
    p[32] = f2bf(x2 * c + x1 * s);
}

// ---------------- V slice of kv -> v_t (B,H,128,S) bf16 ----------------
__global__ __launch_bounds__(256) void transpose_v(const u16* __restrict__ kv,
                                                   u16* __restrict__ vt, int S) {
    __shared__ u16 tile[64][72];
    int bh = blockIdx.z; int b = bh >> 4, h = bh & 15;
    int s0 = blockIdx.x * 64, d0 = blockIdx.y * 64;
    int t = threadIdx.x;
#pragma unroll
    for (int i = 0; i < 16; i++) {
        int idx = t + i * 256; int sl = idx >> 6, dl = idx & 63;
        tile[sl][dl] = kv[(size_t)(b * S + s0 + sl) * 4096 + 2048 + h * 128 + d0 + dl];
    }
    __syncthreads();
#pragma unroll
    for (int i = 0; i < 16; i++) {
        int idx = t + i * 256; int dl = idx >> 6, sl = idx & 63;
        vt[((size_t)(bh * 128 + d0 + dl)) * S + s0 + sl] = tile[sl][dl];
    }
}

// ---------------- Flash MLA attention v2b: LDS-staged K/V, paired q-tiles ----------------
// grid: (16 q-tile pairs, B*H). 256 thr = 4 waves; block handles q-tiles (p, 31-p)
// sequentially -> every block runs exactly 33 k-tile iterations (balanced).
// K tile = 64 keys x 192 dims = 24 chunks(16B)/row -> 1536 chunks = 6 iters of 256 thr.
// (Round-2 bug: used 12 chunks/row -> staged only dims 0..95, poison in 96..191.)
// V^T tile = 128 dims x 64 keys = 8 chunks/row -> 1024 chunks = 4 iters.
__global__ __launch_bounds__(256) void mla_attn(const u16* __restrict__ qc,
                                                const u16* __restrict__ qr,
                                                const u16* __restrict__ kvbuf,
                                                const u16* __restrict__ kr,
                                                const u16* __restrict__ vt,
                                                u16* __restrict__ out, int S) {
    __shared__ __align__(16) u16 Kl[64 * 200];       // 64 keys x 192 dims, stride 200 (400B: 2-way only)
    __shared__ __align__(16) u16 Vl[128 * 72];       // 128 dims x 64 keys, stride 72 (144B: 2-way only)
    __shared__ __align__(16) u16 Plds[4][16 * 72];   // per-wave P round-trip
    const float scale = 0.07216878364870323f;        // 1/sqrt(192)
    int bh = blockIdx.y; int b = bh >> 4, h = bh & 15;
    int pair = blockIdx.x;
    int t = threadIdx.x, w = t >> 6, l = t & 63;
    int lm = l & 15, lq = l >> 4;

    short8 kreg[6], vreg[4];
    auto load_tile = [&](int kbase) {
#pragma unroll
        for (int c = 0; c < 6; c++) {                 // K: 64 rows x 24 chunks(16B)
            int idx = t + c * 256;
            int row = idx / 24, col = (idx % 24) * 8;
            const u16* src = (col < 128)
                ? kvbuf + (size_t)(b * S + kbase + row) * 4096 + h * 128 + col
                : kr + (size_t)(b * S + kbase + row) * 64 + (col - 128);
            kreg[c] = *(const short8*)src;
        }
#pragma unroll
        for (int c = 0; c < 4; c++) {                 // V^T: 128 rows x 8 chunks(16B)
            int idx = t + c * 256;
            int row = idx >> 3, col = (idx & 7) * 8;
            vreg[c] = *(const short8*)(vt + ((size_t)bh * 128 + row) * S + kbase + col);
        }
    };

    for (int half = 0; half < 2; half++) {
        int qt = half ? (31 - pair) : pair;
        int qrow = qt * 64 + w * 16;
        int ntiles = qt + 1;

        // Q A-frags in registers: A[m=lane&15][k=lq*8+j]
        short8 aq[6];
        {
            const u16* qc_row = qc + (size_t)(b * S + qrow + lm) * 2048 + h * 128;
#pragma unroll
            for (int ks = 0; ks < 4; ks++) aq[ks] = *(const short8*)(qc_row + ks * 32 + lq * 8);
            const u16* qr_row = qr + (size_t)(b * S + qrow + lm) * 1024 + h * 64;
#pragma unroll
            for (int ks = 0; ks < 2; ks++) aq[4 + ks] = *(const short8*)(qr_row + ks * 32 + lq * 8);
        }

        f32x4 o[8] = {};
        float m_r[4], l_r[4];
#pragma unroll
        for (int r = 0; r < 4; r++) { m_r[r] = -INFINITY; l_r[r] = 0.f; }

        load_tile(0);
        for (int kt = 0; kt < ntiles; kt++) {
            int kbase = kt * 64;
            __syncthreads();                          // prior iter's LDS reads done
#pragma unroll
            for (int c = 0; c < 6; c++) {
                int idx = t + c * 256;
                int row = idx / 24, col = (idx % 24) * 8;
                *(short8*)(Kl + row * 200 + col) = kreg[c];
            }
#pragma unroll
            for (int c = 0; c < 4; c++) {
                int idx = t + c * 256;
                int row = idx >> 3, col = (idx & 7) * 8;
                *(short8*)(Vl + row * 72 + col) = vreg[c];
            }
            __syncthreads();                          // staging visible to all waves
            if (kt + 1 < ntiles) load_tile(kbase + 64);   // overlaps compute below

            f32x4 acc[4] = {};
#pragma unroll
            for (int ks = 0; ks < 6; ks++) {
#pragma unroll
                for (int nt = 0; nt < 4; nt++) {
                    short8 bk = *(const short8*)(Kl + (nt * 16 + lm) * 200 + ks * 32 + lq * 8);
                    acc[nt] = __builtin_amdgcn_mfma_f32_16x16x32_bf16(aq[ks], bk, acc[nt], 0, 0, 0);
                }
            }
            bool need_mask = (kbase + 63 > qrow);     // wave-uniform
#pragma unroll
            for (int nt = 0; nt < 4; nt++) {
#pragma unroll
                for (int r = 0; r < 4; r++) {
                    float s = acc[nt][r] * scale;
                    if (need_mask) {
                        int ki = kbase + nt * 16 + lm;
                        int qi = qrow + lq * 4 + r;
                        if (ki > qi) s = -INFINITY;
                    }
                    acc[nt][r] = s;
                }
            }
            // online softmax: rows live in 16-lane groups, 4 rows per lane via regs
            float mnew[4], alpha[4];
#pragma unroll
            for (int r = 0; r < 4; r++) {
                float mx = fmaxf(fmaxf(acc[0][r], acc[1][r]), fmaxf(acc[2][r], acc[3][r]));
                mx = fmaxf(mx, __shfl_xor(mx, 1));
                mx = fmaxf(mx, __shfl_xor(mx, 2));
                mx = fmaxf(mx, __shfl_xor(mx, 4));
                mx = fmaxf(mx, __shfl_xor(mx, 8));
                mnew[r] = fmaxf(m_r[r], mx);
                alpha[r] = __expf(m_r[r] - mnew[r]);
                m_r[r] = mnew[r];
            }
            u16* pl = Plds[w];
            float rs[4] = {0.f, 0.f, 0.f, 0.f};
#pragma unroll
            for (int nt = 0; nt < 4; nt++) {
#pragma unroll
                for (int r = 0; r < 4; r++) {
                    float p = __expf(acc[nt][r] - mnew[r]);
                    rs[r] += p;
                    pl[(lq * 4 + r) * 72 + nt * 16 + lm] = f2bf(p);
                }
            }
#pragma unroll
            for (int r = 0; r < 4; r++) {
                float x = rs[r];
                x += __shfl_xor(x, 1); x += __shfl_xor(x, 2);
                x += __shfl_xor(x, 4); x += __shfl_xor(x, 8);
                l_r[r] = l_r[r] * alpha[r] + x;
            }
#pragma unroll
            for (int nt = 0; nt < 8; nt++)
#pragma unroll
                for (int r = 0; r < 4; r++) o[nt][r] *= alpha[r];
            // P back as A-frags (same wave wrote it; compiler inserts lgkmcnt waits)
            short8 ap[2];
#pragma unroll
            for (int kp = 0; kp < 2; kp++)
                ap[kp] = *(const short8*)(pl + lm * 72 + kp * 32 + lq * 8);
#pragma unroll
            for (int kp = 0; kp < 2; kp++) {
#pragma unroll
                for (int nt = 0; nt < 8; nt++) {
                    short8 bv = *(const short8*)(Vl + (size_t)(nt * 16 + lm) * 72 + kp * 32 + lq * 8);
                    o[nt] = __builtin_amdgcn_mfma_f32_16x16x32_bf16(ap[kp], bv, o[nt], 0, 0, 0);
                }
            }
        }
        // epilogue: divide by row sums, store bf16
#pragma unroll
        for (int r = 0; r < 4; r++) l_r[r] = 1.0f / l_r[r];
        u16* orow = out + (size_t)(b * S + qrow) * 2048 + h * 128;
#pragma unroll
        for (int nt = 0; nt < 8; nt++)
#pragma unroll
            for (int r = 0; r < 4; r++)
                orow[(size_t)(lq * 4 + r) * 2048 + nt * 16 + lm] = f2bf(o[nt][r] * l_r[r]);
    }
}

extern "C" void kernel_launch(void* const* d_in, const int* in_sizes, int n_in,
                              void* d_out, int out_size, void* d_ws, size_t ws_size,
                              hipStream_t stream) {
    const int B = 2, S = 2048, D = 2048, H = 16;
    const int M = B * S;                       // 4096
    const float* x    = (const float*)d_in[0];
    const float* Wq   = (const float*)d_in[1];
    const float* Wqr  = (const float*)d_in[2];
    const float* Wkvd = (const float*)d_in[3];
    const float* Wkvu = (const float*)d_in[4];
    const float* Wkr  = (const float*)d_in[5];
    const float* Wo   = (const float*)d_in[6];

    u16* p = (u16*)d_ws;
    u16* xb    = p; p += (size_t)M * D;          // 8.39M
    u16* WqT   = p; p += (size_t)2048 * 2048;
    u16* WqrT  = p; p += (size_t)1024 * 2048;
    u16* WkvdT = p; p += (size_t)512 * 2048;
    u16* WkvuT = p; p += (size_t)4096 * 512;
    u16* WkrT  = p; p += (size_t)64 * 2048;
    u16* WoT   = p; p += (size_t)2048 * 2048;
    u16* q_c   = p; p += (size_t)M * 2048;
    u16* q_r   = p; p += (size_t)M * 1024;
    u16* c_kv  = p; p += (size_t)M * 512;
    u16* k_r   = p; p += (size_t)M * 64;
    u16* kv    = p; p += (size_t)M * 4096;
    u16* v_t   = p; p += (size_t)B * H * 128 * S;
    u16* attn  = p; p += (size_t)M * 2048;

    // 1) casts / transposes
    cast_f32_bf16<<<(M * D) / 4 / 256, 256, 0, stream>>>(x, xb, M * D);
    transpose_cast<<<dim3(32, 32), 256, 0, stream>>>(Wq,   WqT,   2048, 2048);
    transpose_cast<<<dim3(32, 16), 256, 0, stream>>>(Wqr,  WqrT,  2048, 1024);
    transpose_cast<<<dim3(32, 8),  256, 0, stream>>>(Wkvd, WkvdT, 2048, 512);
    transpose_cast<<<dim3(8, 64),  256, 0, stream>>>(Wkvu, WkvuT, 512, 4096);
    transpose_cast<<<dim3(32, 1),  256, 0, stream>>>(Wkr,  WkrT,  2048, 64);
    transpose_cast<<<dim3(32, 32), 256, 0, stream>>>(Wo,   WoT,   2048, 2048);

    // 2) projections
    gemm_bt<0><<<dim3(32, 16), 256, 0, stream>>>(xb, WqT,   q_c,  M, 2048, 2048);
    gemm_bt<0><<<dim3(32, 8),  256, 0, stream>>>(xb, WqrT,  q_r,  M, 1024, 2048);
    gemm_bt<0><<<dim3(32, 4),  256, 0, stream>>>(xb, WkvdT, c_kv, M, 512, 2048);
    gemm_bt<0><<<dim3(32, 1),  256, 0, stream>>>(xb, WkrT,  k_r,  M, 64, 2048);

    // 3) RoPE (in place)
    rope_kernel<<<(M * 16 * 32) / 256, 256, 0, stream>>>(q_r, M, 16, S - 1);
    rope_kernel<<<(M * 32) / 256, 256, 0, stream>>>(k_r, M, 1, S - 1);

    // 4) kv up-projection, V transpose
    gemm_bt<0><<<dim3(32, 32), 256, 0, stream>>>(c_kv, WkvuT, kv, M, 4096, 512);
    transpose_v<<<dim3(32, 2, 32), 256, 0, stream>>>(kv, v_t, S);

    // 5) attention (paired q-tiles for causal load balance)
    mla_attn<<<dim3(16, 32), 256, 0, stream>>>(q_c, q_r, kv, k_r, v_t, attn, S);

    // 6) output projection -> fp32 d_out
    gemm_bt<1><<<dim3(32, 16), 256, 0, stream>>>(attn, WoT, d_out, M, 2048, 2048);
}

// Round 4
// 586.582 us; speedup vs baseline: 1.7948x; 1.0230x over previous
//
#include <hip/hip_runtime.h>
#include <hip/hip_bf16.h>
#include <cstdint>
#include <cstddef>

typedef unsigned short u16;
typedef __attribute__((ext_vector_type(8))) short short8;   // 8 bf16 = 4 VGPRs (MFMA A/B frag)
typedef __attribute__((ext_vector_type(4))) float f32x4;    // MFMA C/D frag

__device__ __forceinline__ u16 f2bf(float f) {
    union { float f; uint32_t u; } v; v.f = f;
    uint32_t u = v.u;
    return (u16)((u + 0x7fffu + ((u >> 16) & 1u)) >> 16);   // RNE
}
__device__ __forceinline__ float bf2f(u16 u) {
    union { uint32_t u; float f; } v; v.u = ((uint32_t)u) << 16;
    return v.f;
}

// async global->LDS 16B copy (m97: global_load_lds_dwordx4).
// LDS dest is wave-uniform base + lane*16; global addr is per-lane.
__device__ __forceinline__ void async_cp16(const u16* g, u16* l) {
    __builtin_amdgcn_global_load_lds(
        (const __attribute__((address_space(1))) unsigned int*)g,
        (__attribute__((address_space(3))) unsigned int*)l, 16, 0, 0);
}

// ---------------- cast fp32 -> bf16 (vectorized) ----------------
__global__ __launch_bounds__(256) void cast_f32_bf16(const float* __restrict__ in,
                                                     u16* __restrict__ out, int n) {
    int i = (blockIdx.x * 256 + threadIdx.x) * 4;
    if (i >= n) return;
    float4 v = *(const float4*)(in + i);
    ushort4 r;
    r.x = f2bf(v.x); r.y = f2bf(v.y); r.z = f2bf(v.z); r.w = f2bf(v.w);
    *(ushort4*)(out + i) = r;
}

// ---------------- W (K,N) fp32 -> Wt (N,K) bf16, 64x64 LDS tiles ----------------
__global__ __launch_bounds__(256) void transpose_cast(const float* __restrict__ W,
                                                      u16* __restrict__ Wt, int K, int N) {
    __shared__ u16 tile[64][72];
    int kt = blockIdx.x * 64, nt = blockIdx.y * 64;
    int t = threadIdx.x;
#pragma unroll
    for (int i = 0; i < 16; i++) {
        int idx = t + i * 256; int kl = idx >> 6, nl = idx & 63;
        tile[kl][nl] = f2bf(W[(size_t)(kt + kl) * N + nt + nl]);
    }
    __syncthreads();
#pragma unroll
    for (int i = 0; i < 16; i++) {
        int idx = t + i * 256; int nl = idx >> 6, kl = idx & 63;
        Wt[(size_t)(nt + nl) * K + kt + kl] = tile[kl][nl];
    }
}

// ---------------- bf16 GEMM v2 (m97 structure): C(M,N) = A(M,K) @ Bt(N,K)^T ----------------
// 128x128 tile, BK=32, 4 waves in 2x2 (each 64x64), mfma 16x16x32 bf16.
// Staging via global_load_lds width=16: unpadded 128x32 LDS tiles (wave-uniform
// base + lane*16 constraint forbids padding). 2 barriers per K-step.
template <int OUTF32>
__global__ __launch_bounds__(256) void gemm_bt(const u16* __restrict__ A,
                                               const u16* __restrict__ Bt,
                                               void* __restrict__ Cout,
                                               int M, int N, int K) {
    __shared__ __align__(16) u16 Al[128 * 32];   // 8 KB, rows of 32 elems (64 B), no pad
    __shared__ __align__(16) u16 Bl[128 * 32];
    int m0 = blockIdx.x * 128, n0 = blockIdx.y * 128;
    int t = threadIdx.x;
    int w = t >> 6, l = t & 63;
    int lm = l & 15, lq = l >> 4;
    int wm = (w >> 1) * 64, wn = (w & 1) * 64;
    f32x4 acc[4][4] = {};

    for (int k0 = 0; k0 < K; k0 += 32) {
        // async staging: 512 chunks (16B) per tile; wave w owns chunks [w*128, w*128+128)
#pragma unroll
        for (int c = 0; c < 2; c++) {
            int chunk = w * 128 + c * 64 + l;          // per-lane chunk id
            int row = chunk >> 2, col8 = (chunk & 3) * 8;
            async_cp16(A + (size_t)(m0 + row) * K + k0 + col8,
                       Al + (w * 128 + c * 64) * 8);   // wave-uniform LDS base
            int brow = n0 + row; if (brow >= N) brow = N - 1;   // clamp (partial-N tiles)
            async_cp16(Bt + (size_t)brow * K + k0 + col8,
                       Bl + (w * 128 + c * 64) * 8);
        }
        __syncthreads();                               // drains vmcnt -> staging visible
        short8 af[4], bfr[4];
#pragma unroll
        for (int mt = 0; mt < 4; mt++)
            af[mt] = *(const short8*)(Al + (wm + mt * 16 + lm) * 32 + lq * 8);
#pragma unroll
        for (int nt = 0; nt < 4; nt++)
            bfr[nt] = *(const short8*)(Bl + (wn + nt * 16 + lm) * 32 + lq * 8);
#pragma unroll
        for (int mt = 0; mt < 4; mt++)
#pragma unroll
            for (int nt = 0; nt < 4; nt++)
                acc[mt][nt] = __builtin_amdgcn_mfma_f32_16x16x32_bf16(af[mt], bfr[nt], acc[mt][nt], 0, 0, 0);
        __syncthreads();                               // frag reads done before next staging
    }
    // epilogue: C layout col=lane&15, row=(lane>>4)*4+reg
#pragma unroll
    for (int mt = 0; mt < 4; mt++) {
#pragma unroll
        for (int nt = 0; nt < 4; nt++) {
            int col = n0 + wn + nt * 16 + lm;
            if (col < N) {
#pragma unroll
                for (int r = 0; r < 4; r++) {
                    int row = m0 + wm + mt * 16 + lq * 4 + r;
                    if (OUTF32) ((float*)Cout)[(size_t)row * N + col] = acc[mt][nt][r];
                    else        ((u16*)Cout)[(size_t)row * N + col] = f2bf(acc[mt][nt][r]);
                }
            }
        }
    }
}

// ---------------- RoPE in-place on (rows, nheads*64) bf16 ----------------
__global__ __launch_bounds__(256) void rope_kernel(u16* __restrict__ x, int rows,
                                                   int nheads, int Smask) {
    int i = blockIdx.x * 256 + threadIdx.x;
    int total = rows * nheads * 32;
    if (i >= total) return;
    int j = i & 31;
    int h = (i >> 5) % nheads;
    int row = i / (32 * nheads);
    int pos = row & Smask;                       // pos = s (S power of two)
    // inv_freq = 10000^(-j/32) = 2^(-j*log2(10000)/32)
    float f = exp2f((float)j * -0.4152410118609828f);
    float ang = (float)pos * f;
    float c = cosf(ang), s = sinf(ang);
    u16* p = x + (size_t)row * (nheads * 64) + h * 64 + j;
    float x1 = bf2f(p[0]), x2 = bf2f(p[32]);
    p[0]  = f2bf(x1 * c - x2 * s);
    p[32] = f2bf(x2 * c + x1 * s);
}

// ---------------- V slice of kv -> v_t (B,H,128,S) bf16 ----------------
__global__ __launch_bounds__(256) void transpose_v(const u16* __restrict__ kv,
                                                   u16* __restrict__ vt, int S) {
    __shared__ u16 tile[64][72];
    int bh = blockIdx.z; int b = bh >> 4, h = bh & 15;
    int s0 = blockIdx.x * 64, d0 = blockIdx.y * 64;
    int t = threadIdx.x;
#pragma unroll
    for (int i = 0; i < 16; i++) {
        int idx = t + i * 256; int sl = idx >> 6, dl = idx & 63;
        tile[sl][dl] = kv[(size_t)(b * S + s0 + sl) * 4096 + 2048 + h * 128 + d0 + dl];
    }
    __syncthreads();
#pragma unroll
    for (int i = 0; i < 16; i++) {
        int idx = t + i * 256; int dl = idx >> 6, sl = idx & 63;
        vt[((size_t)(bh * 128 + d0 + dl)) * S + s0 + sl] = tile[sl][dl];
    }
}

// ---------------- Flash MLA attention v2b: LDS-staged K/V, paired q-tiles ----------------
// (unchanged this round; LDS-conflict/latency bound — next round's target)
__global__ __launch_bounds__(256) void mla_attn(const u16* __restrict__ qc,
                                                const u16* __restrict__ qr,
                                                const u16* __restrict__ kvbuf,
                                                const u16* __restrict__ kr,
                                                const u16* __restrict__ vt,
                                                u16* __restrict__ out, int S) {
    __shared__ __align__(16) u16 Kl[64 * 200];       // 64 keys x 192 dims, stride 200
    __shared__ __align__(16) u16 Vl[128 * 72];       // 128 dims x 64 keys, stride 72
    __shared__ __align__(16) u16 Plds[4][16 * 72];   // per-wave P round-trip
    const float scale = 0.07216878364870323f;        // 1/sqrt(192)
    int bh = blockIdx.y; int b = bh >> 4, h = bh & 15;
    int pair = blockIdx.x;
    int t = threadIdx.x, w = t >> 6, l = t & 63;
    int lm = l & 15, lq = l >> 4;

    short8 kreg[6], vreg[4];
    auto load_tile = [&](int kbase) {
#pragma unroll
        for (int c = 0; c < 6; c++) {                 // K: 64 rows x 24 chunks(16B)
            int idx = t + c * 256;
            int row = idx / 24, col = (idx % 24) * 8;
            const u16* src = (col < 128)
                ? kvbuf + (size_t)(b * S + kbase + row) * 4096 + h * 128 + col
                : kr + (size_t)(b * S + kbase + row) * 64 + (col - 128);
            kreg[c] = *(const short8*)src;
        }
#pragma unroll
        for (int c = 0; c < 4; c++) {                 // V^T: 128 rows x 8 chunks(16B)
            int idx = t + c * 256;
            int row = idx >> 3, col = (idx & 7) * 8;
            vreg[c] = *(const short8*)(vt + ((size_t)bh * 128 + row) * S + kbase + col);
        }
    };

    for (int half = 0; half < 2; half++) {
        int qt = half ? (31 - pair) : pair;
        int qrow = qt * 64 + w * 16;
        int ntiles = qt + 1;

        // Q A-frags in registers: A[m=lane&15][k=lq*8+j]
        short8 aq[6];
        {
            const u16* qc_row = qc + (size_t)(b * S + qrow + lm) * 2048 + h * 128;
#pragma unroll
            for (int ks = 0; ks < 4; ks++) aq[ks] = *(const short8*)(qc_row + ks * 32 + lq * 8);
            const u16* qr_row = qr + (size_t)(b * S + qrow + lm) * 1024 + h * 64;
#pragma unroll
            for (int ks = 0; ks < 2; ks++) aq[4 + ks] = *(const short8*)(qr_row + ks * 32 + lq * 8);
        }

        f32x4 o[8] = {};
        float m_r[4], l_r[4];
#pragma unroll
        for (int r = 0; r < 4; r++) { m_r[r] = -INFINITY; l_r[r] = 0.f; }

        load_tile(0);
        for (int kt = 0; kt < ntiles; kt++) {
            int kbase = kt * 64;
            __syncthreads();                          // prior iter's LDS reads done
#pragma unroll
            for (int c = 0; c < 6; c++) {
                int idx = t + c * 256;
                int row = idx / 24, col = (idx % 24) * 8;
                *(short8*)(Kl + row * 200 + col) = kreg[c];
            }
#pragma unroll
            for (int c = 0; c < 4; c++) {
                int idx = t + c * 256;
                int row = idx >> 3, col = (idx & 7) * 8;
                *(short8*)(Vl + row * 72 + col) = vreg[c];
            }
            __syncthreads();                          // staging visible to all waves
            if (kt + 1 < ntiles) load_tile(kbase + 64);   // overlaps compute below

            f32x4 acc[4] = {};
#pragma unroll
            for (int ks = 0; ks < 6; ks++) {
#pragma unroll
                for (int nt = 0; nt < 4; nt++) {
                    short8 bk = *(const short8*)(Kl + (nt * 16 + lm) * 200 + ks * 32 + lq * 8);
                    acc[nt] = __builtin_amdgcn_mfma_f32_16x16x32_bf16(aq[ks], bk, acc[nt], 0, 0, 0);
                }
            }
            bool need_mask = (kbase + 63 > qrow);     // wave-uniform
#pragma unroll
            for (int nt = 0; nt < 4; nt++) {
#pragma unroll
                for (int r = 0; r < 4; r++) {
                    float s = acc[nt][r] * scale;
                    if (need_mask) {
                        int ki = kbase + nt * 16 + lm;
                        int qi = qrow + lq * 4 + r;
                        if (ki > qi) s = -INFINITY;
                    }
                    acc[nt][r] = s;
                }
            }
            // online softmax: rows live in 16-lane groups, 4 rows per lane via regs
            float mnew[4], alpha[4];
#pragma unroll
            for (int r = 0; r < 4; r++) {
                float mx = fmaxf(fmaxf(acc[0][r], acc[1][r]), fmaxf(acc[2][r], acc[3][r]));
                mx = fmaxf(mx, __shfl_xor(mx, 1));
                mx = fmaxf(mx, __shfl_xor(mx, 2));
                mx = fmaxf(mx, __shfl_xor(mx, 4));
                mx = fmaxf(mx, __shfl_xor(mx, 8));
                mnew[r] = fmaxf(m_r[r], mx);
                alpha[r] = __expf(m_r[r] - mnew[r]);
                m_r[r] = mnew[r];
            }
            u16* pl = Plds[w];
            float rs[4] = {0.f, 0.f, 0.f, 0.f};
#pragma unroll
            for (int nt = 0; nt < 4; nt++) {
#pragma unroll
                for (int r = 0; r < 4; r++) {
                    float p = __expf(acc[nt][r] - mnew[r]);
                    rs[r] += p;
                    pl[(lq * 4 + r) * 72 + nt * 16 + lm] = f2bf(p);
                }
            }
#pragma unroll
            for (int r = 0; r < 4; r++) {
                float x = rs[r];
                x += __shfl_xor(x, 1); x += __shfl_xor(x, 2);
                x += __shfl_xor(x, 4); x += __shfl_xor(x, 8);
                l_r[r] = l_r[r] * alpha[r] + x;
            }
#pragma unroll
            for (int nt = 0; nt < 8; nt++)
#pragma unroll
                for (int r = 0; r < 4; r++) o[nt][r] *= alpha[r];
            // P back as A-frags (same wave wrote it; compiler inserts lgkmcnt waits)
            short8 ap[2];
#pragma unroll
            for (int kp = 0; kp < 2; kp++)
                ap[kp] = *(const short8*)(pl + lm * 72 + kp * 32 + lq * 8);
#pragma unroll
            for (int kp = 0; kp < 2; kp++) {
#pragma unroll
                for (int nt = 0; nt < 8; nt++) {
                    short8 bv = *(const short8*)(Vl + (size_t)(nt * 16 + lm) * 72 + kp * 32 + lq * 8);
                    o[nt] = __builtin_amdgcn_mfma_f32_16x16x32_bf16(ap[kp], bv, o[nt], 0, 0, 0);
                }
            }
        }
        // epilogue: divide by row sums, store bf16
#pragma unroll
        for (int r = 0; r < 4; r++) l_r[r] = 1.0f / l_r[r];
        u16* orow = out + (size_t)(b * S + qrow) * 2048 + h * 128;
#pragma unroll
        for (int nt = 0; nt < 8; nt++)
#pragma unroll
            for (int r = 0; r < 4; r++)
                orow[(size_t)(lq * 4 + r) * 2048 + nt * 16 + lm] = f2bf(o[nt][r] * l_r[r]);
    }
}

extern "C" void kernel_launch(void* const* d_in, const int* in_sizes, int n_in,
                              void* d_out, int out_size, void* d_ws, size_t ws_size,
                              hipStream_t stream) {
    const int B = 2, S = 2048, D = 2048, H = 16;
    const int M = B * S;                       // 4096
    const float* x    = (const float*)d_in[0];
    const float* Wq   = (const float*)d_in[1];
    const float* Wqr  = (const float*)d_in[2];
    const float* Wkvd = (const float*)d_in[3];
    const float* Wkvu = (const float*)d_in[4];
    const float* Wkr  = (const float*)d_in[5];
    const float* Wo   = (const float*)d_in[6];

    u16* p = (u16*)d_ws;
    u16* xb    = p; p += (size_t)M * D;          // 8.39M
    u16* WqT   = p; p += (size_t)2048 * 2048;
    u16* WqrT  = p; p += (size_t)1024 * 2048;
    u16* WkvdT = p; p += (size_t)512 * 2048;
    u16* WkvuT = p; p += (size_t)4096 * 512;
    u16* WkrT  = p; p += (size_t)64 * 2048;
    u16* WoT   = p; p += (size_t)2048 * 2048;
    u16* q_c   = p; p += (size_t)M * 2048;
    u16* q_r   = p; p += (size_t)M * 1024;
    u16* c_kv  = p; p += (size_t)M * 512;
    u16* k_r   = p; p += (size_t)M * 64;
    u16* kv    = p; p += (size_t)M * 4096;
    u16* v_t   = p; p += (size_t)B * H * 128 * S;
    u16* attn  = p; p += (size_t)M * 2048;

    // 1) casts / transposes
    cast_f32_bf16<<<(M * D) / 4 / 256, 256, 0, stream>>>(x, xb, M * D);
    transpose_cast<<<dim3(32, 32), 256, 0, stream>>>(Wq,   WqT,   2048, 2048);
    transpose_cast<<<dim3(32, 16), 256, 0, stream>>>(Wqr,  WqrT,  2048, 1024);
    transpose_cast<<<dim3(32, 8),  256, 0, stream>>>(Wkvd, WkvdT, 2048, 512);
    transpose_cast<<<dim3(8, 64),  256, 0, stream>>>(Wkvu, WkvuT, 512, 4096);
    transpose_cast<<<dim3(32, 1),  256, 0, stream>>>(Wkr,  WkrT,  2048, 64);
    transpose_cast<<<dim3(32, 32), 256, 0, stream>>>(Wo,   WoT,   2048, 2048);

    // 2) projections
    gemm_bt<0><<<dim3(32, 16), 256, 0, stream>>>(xb, WqT,   q_c,  M, 2048, 2048);
    gemm_bt<0><<<dim3(32, 8),  256, 0, stream>>>(xb, WqrT,  q_r,  M, 1024, 2048);
    gemm_bt<0><<<dim3(32, 4),  256, 0, stream>>>(xb, WkvdT, c_kv, M, 512, 2048);
    gemm_bt<0><<<dim3(32, 1),  256, 0, stream>>>(xb, WkrT,  k_r,  M, 64, 2048);

    // 3) RoPE (in place)
    rope_kernel<<<(M * 16 * 32) / 256, 256, 0, stream>>>(q_r, M, 16, S - 1);
    rope_kernel<<<(M * 32) / 256, 256, 0, stream>>>(k_r, M, 1, S - 1);

    // 4) kv up-projection, V transpose
    gemm_bt<0><<<dim3(32, 32), 256, 0, stream>>>(c_kv, WkvuT, kv, M, 4096, 512);
    transpose_v<<<dim3(32, 2, 32), 256, 0, stream>>>(kv, v_t, S);

    // 5) attention (paired q-tiles for causal load balance)
    mla_attn<<<dim3(16, 32), 256, 0, stream>>>(q_c, q_r, kv, k_r, v_t, attn, S);

    // 6) output projection -> fp32 d_out
    gemm_bt<1><<<dim3(32, 16), 256, 0, stream>>>(attn, WoT, d_out, M, 2048, 2048);
}

// Round 5
// 529.594 us; speedup vs baseline: 1.9880x; 1.1076x over previous
//
#include <hip/hip_runtime.h>
#include <hip/hip_bf16.h>
#include <cstdint>
#include <cstddef>

typedef unsigned short u16;
typedef __attribute__((ext_vector_type(8))) short short8;   // 8 bf16 = 4 VGPRs (MFMA A/B frag)
typedef __attribute__((ext_vector_type(4))) float f32x4;    // MFMA C/D frag

__device__ __forceinline__ u16 f2bf(float f) {
    union { float f; uint32_t u; } v; v.f = f;
    uint32_t u = v.u;
    return (u16)((u + 0x7fffu + ((u >> 16) & 1u)) >> 16);   // RNE
}
__device__ __forceinline__ float bf2f(u16 u) {
    union { uint32_t u; float f; } v; v.u = ((uint32_t)u) << 16;
    return v.f;
}

// async global->LDS 16B copy (m97: global_load_lds_dwordx4).
// LDS dest is wave-uniform base + lane*16; global addr is per-lane.
__device__ __forceinline__ void async_cp16(const u16* g, u16* l) {
    __builtin_amdgcn_global_load_lds(
        (const __attribute__((address_space(1))) unsigned int*)g,
        (__attribute__((address_space(3))) unsigned int*)l, 16, 0, 0);
}

// ---------------- cast fp32 -> bf16 (vectorized) ----------------
__global__ __launch_bounds__(256) void cast_f32_bf16(const float* __restrict__ in,
                                                     u16* __restrict__ out, int n) {
    int i = (blockIdx.x * 256 + threadIdx.x) * 4;
    if (i >= n) return;
    float4 v = *(const float4*)(in + i);
    ushort4 r;
    r.x = f2bf(v.x); r.y = f2bf(v.y); r.z = f2bf(v.z); r.w = f2bf(v.w);
    *(ushort4*)(out + i) = r;
}

// ---------------- W (K,N) fp32 -> Wt (N,K) bf16 (optionally pre-scaled) ----------------
__global__ __launch_bounds__(256) void transpose_cast(const float* __restrict__ W,
                                                      u16* __restrict__ Wt, int K, int N,
                                                      float smul) {
    __shared__ u16 tile[64][72];
    int kt = blockIdx.x * 64, nt = blockIdx.y * 64;
    int t = threadIdx.x;
#pragma unroll
    for (int i = 0; i < 16; i++) {
        int idx = t + i * 256; int kl = idx >> 6, nl = idx & 63;
        tile[kl][nl] = f2bf(W[(size_t)(kt + kl) * N + nt + nl] * smul);
    }
    __syncthreads();
#pragma unroll
    for (int i = 0; i < 16; i++) {
        int idx = t + i * 256; int nl = idx >> 6, kl = idx & 63;
        Wt[(size_t)(nt + nl) * K + kt + kl] = tile[kl][nl];
    }
}

// ---------------- bf16 GEMM (m97 structure): C(M,N) = A(M,K) @ Bt(N,K)^T ----------------
template <int OUTF32>
__global__ __launch_bounds__(256) void gemm_bt(const u16* __restrict__ A,
                                               const u16* __restrict__ Bt,
                                               void* __restrict__ Cout,
                                               int M, int N, int K) {
    __shared__ __align__(16) u16 Al[128 * 32];   // 8 KB, rows of 32 elems (64 B), no pad
    __shared__ __align__(16) u16 Bl[128 * 32];
    int m0 = blockIdx.x * 128, n0 = blockIdx.y * 128;
    int t = threadIdx.x;
    int w = t >> 6, l = t & 63;
    int lm = l & 15, lq = l >> 4;
    int wm = (w >> 1) * 64, wn = (w & 1) * 64;
    f32x4 acc[4][4] = {};

    for (int k0 = 0; k0 < K; k0 += 32) {
#pragma unroll
        for (int c = 0; c < 2; c++) {
            int chunk = w * 128 + c * 64 + l;          // per-lane chunk id
            int row = chunk >> 2, col8 = (chunk & 3) * 8;
            async_cp16(A + (size_t)(m0 + row) * K + k0 + col8,
                       Al + (w * 128 + c * 64) * 8);   // wave-uniform LDS base
            int brow = n0 + row; if (brow >= N) brow = N - 1;   // clamp (partial-N tiles)
            async_cp16(Bt + (size_t)brow * K + k0 + col8,
                       Bl + (w * 128 + c * 64) * 8);
        }
        __syncthreads();
        short8 af[4], bfr[4];
#pragma unroll
        for (int mt = 0; mt < 4; mt++)
            af[mt] = *(const short8*)(Al + (wm + mt * 16 + lm) * 32 + lq * 8);
#pragma unroll
        for (int nt = 0; nt < 4; nt++)
            bfr[nt] = *(const short8*)(Bl + (wn + nt * 16 + lm) * 32 + lq * 8);
#pragma unroll
        for (int mt = 0; mt < 4; mt++)
#pragma unroll
            for (int nt = 0; nt < 4; nt++)
                acc[mt][nt] = __builtin_amdgcn_mfma_f32_16x16x32_bf16(af[mt], bfr[nt], acc[mt][nt], 0, 0, 0);
        __syncthreads();
    }
#pragma unroll
    for (int mt = 0; mt < 4; mt++) {
#pragma unroll
        for (int nt = 0; nt < 4; nt++) {
            int col = n0 + wn + nt * 16 + lm;
            if (col < N) {
#pragma unroll
                for (int r = 0; r < 4; r++) {
                    int row = m0 + wm + mt * 16 + lq * 4 + r;
                    if (OUTF32) ((float*)Cout)[(size_t)row * N + col] = acc[mt][nt][r];
                    else        ((u16*)Cout)[(size_t)row * N + col] = f2bf(acc[mt][nt][r]);
                }
            }
        }
    }
}

// ---------------- RoPE in-place on (rows, nheads*64) bf16 ----------------
__global__ __launch_bounds__(256) void rope_kernel(u16* __restrict__ x, int rows,
                                                   int nheads, int Smask) {
    int i = blockIdx.x * 256 + threadIdx.x;
    int total = rows * nheads * 32;
    if (i >= total) return;
    int j = i & 31;
    int h = (i >> 5) % nheads;
    int row = i / (32 * nheads);
    int pos = row & Smask;                       // pos = s (S power of two)
    float f = exp2f((float)j * -0.4152410118609828f);
    float ang = (float)pos * f;
    float c = cosf(ang), s = sinf(ang);
    u16* p = x + (size_t)row * (nheads * 64) + h * 64 + j;
    float x1 = bf2f(p[0]), x2 = bf2f(p[32]);
    p[0]  = f2bf(x1 * c - x2 * s);
    p[32] = f2bf(x2 * c + x1 * s);
}

// ---------------- V slice of kv -> v_t (B,H,128,S) bf16 ----------------
__global__ __launch_bounds__(256) void transpose_v(const u16* __restrict__ kv,
                                                   u16* __restrict__ vt, int S) {
    __shared__ u16 tile[64][72];
    int bh = blockIdx.z; int b = bh >> 4, h = bh & 15;
    int s0 = blockIdx.x * 64, d0 = blockIdx.y * 64;
    int t = threadIdx.x;
#pragma unroll
    for (int i = 0; i < 16; i++) {
        int idx = t + i * 256; int sl = idx >> 6, dl = idx & 63;
        tile[sl][dl] = kv[(size_t)(b * S + s0 + sl) * 4096 + 2048 + h * 128 + d0 + dl];
    }
    __syncthreads();
#pragma unroll
    for (int i = 0; i < 16; i++) {
        int idx = t + i * 256; int dl = idx >> 6, sl = idx & 63;
        vt[((size_t)(bh * 128 + d0 + dl)) * S + s0 + sl] = tile[sl][dl];
    }
}

// ---------------- Flash MLA attention v3: transposed-score formulation ----------------
// S^T = K·Q^T (A=K, B=Q) -> C layout: col(lane&15)=q-row, row(lq*4+r)=key.
// Each lane owns ONE q-row: softmax max/sum = intra-lane over 16 regs + 2 shfl (xor16,32).
// O^T = V^T·P^T (A=V^T, B=P) -> C: col=q, row=dim; stores pack to 8B.
// Q is PRE-SCALED by 1/sqrt(192) (folded into Wq/Wq_rope at transpose_cast).
// P round-trip: write 4x ds_write_b64 [q][key], read 2x b128 B-frags.
__global__ __launch_bounds__(256) void mla_attn(const u16* __restrict__ qc,
                                                const u16* __restrict__ qr,
                                                const u16* __restrict__ kvbuf,
                                                const u16* __restrict__ kr,
                                                const u16* __restrict__ vt,
                                                u16* __restrict__ out, int S) {
    __shared__ __align__(16) u16 Kl[64 * 200];       // 64 keys x 192 dims, stride 200
    __shared__ __align__(16) u16 Vl[128 * 72];       // 128 dims x 64 keys, stride 72
    __shared__ __align__(16) u16 Plds[4][16 * 72];   // per-wave P[q][key], stride 72
    int bh = blockIdx.y; int b = bh >> 4, h = bh & 15;
    int pair = blockIdx.x;
    int t = threadIdx.x, w = t >> 6, l = t & 63;
    int lm = l & 15, lq = l >> 4;

    short8 kreg[6], vreg[4];
    auto load_tile = [&](int kbase) {
#pragma unroll
        for (int c = 0; c < 6; c++) {                 // K: 64 rows x 24 chunks(16B)
            int idx = t + c * 256;
            int row = idx / 24, col = (idx % 24) * 8;
            const u16* src = (col < 128)
                ? kvbuf + (size_t)(b * S + kbase + row) * 4096 + h * 128 + col
                : kr + (size_t)(b * S + kbase + row) * 64 + (col - 128);
            kreg[c] = *(const short8*)src;
        }
#pragma unroll
        for (int c = 0; c < 4; c++) {                 // V^T: 128 rows x 8 chunks(16B)
            int idx = t + c * 256;
            int row = idx >> 3, col = (idx & 7) * 8;
            vreg[c] = *(const short8*)(vt + ((size_t)bh * 128 + row) * S + kbase + col);
        }
    };

    for (int half = 0; half < 2; half++) {
        int qt = half ? (31 - pair) : pair;
        int qrow = qt * 64 + w * 16;                  // this wave's 16 q-rows
        int ntiles = qt + 1;

        // Q B-frags: B[n=q=lane&15][k=lq*8+j] (pre-scaled)
        short8 bq[6];
        {
            const u16* qc_row = qc + (size_t)(b * S + qrow + lm) * 2048 + h * 128;
#pragma unroll
            for (int ks = 0; ks < 4; ks++) bq[ks] = *(const short8*)(qc_row + ks * 32 + lq * 8);
            const u16* qr_row = qr + (size_t)(b * S + qrow + lm) * 1024 + h * 64;
#pragma unroll
            for (int ks = 0; ks < 2; ks++) bq[4 + ks] = *(const short8*)(qr_row + ks * 32 + lq * 8);
        }

        f32x4 o[8] = {};                              // O^T accs: 8 dim-tiles x (4 rows)
        float m_s = -INFINITY, l_s = 0.f;             // per-lane state for q-row (qrow+lm)

        load_tile(0);
        for (int kt = 0; kt < ntiles; kt++) {
            int kbase = kt * 64;
            __syncthreads();                          // prior iter's LDS reads done
#pragma unroll
            for (int c = 0; c < 6; c++) {
                int idx = t + c * 256;
                int row = idx / 24, col = (idx % 24) * 8;
                *(short8*)(Kl + row * 200 + col) = kreg[c];
            }
#pragma unroll
            for (int c = 0; c < 4; c++) {
                int idx = t + c * 256;
                int row = idx >> 3, col = (idx & 7) * 8;
                *(short8*)(Vl + row * 72 + col) = vreg[c];
            }
            __syncthreads();                          // staging visible to all waves
            if (kt + 1 < ntiles) load_tile(kbase + 64);   // overlaps compute below

            if (kbase > qrow + 15) continue;          // fully-masked for this wave

            // S^T: acc[mt][r] = S[q=qrow+lm][key=kbase+mt*16+lq*4+r]
            f32x4 acc[4] = {};
#pragma unroll
            for (int ks = 0; ks < 6; ks++) {
#pragma unroll
                for (int mt = 0; mt < 4; mt++) {
                    short8 ak = *(const short8*)(Kl + (mt * 16 + lm) * 200 + ks * 32 + lq * 8);
                    acc[mt] = __builtin_amdgcn_mfma_f32_16x16x32_bf16(ak, bq[ks], acc[mt], 0, 0, 0);
                }
            }
            if (kbase + 63 > qrow) {                  // diagonal tile: causal mask
                int qi = qrow + lm;
#pragma unroll
                for (int mt = 0; mt < 4; mt++)
#pragma unroll
                    for (int r = 0; r < 4; r++) {
                        int ki = kbase + mt * 16 + lq * 4 + r;
                        if (ki > qi) acc[mt][r] = -INFINITY;
                    }
            }
            // online softmax: intra-lane over 16 regs, then xor16/xor32 across lq replicas
            float mx = -INFINITY;
#pragma unroll
            for (int mt = 0; mt < 4; mt++)
#pragma unroll
                for (int r = 0; r < 4; r++) mx = fmaxf(mx, acc[mt][r]);
            mx = fmaxf(mx, __shfl_xor(mx, 16));
            mx = fmaxf(mx, __shfl_xor(mx, 32));
            float mnew = fmaxf(m_s, mx);
            float alpha = __expf(m_s - mnew);
            m_s = mnew;

            u16* pl = Plds[w];
            float rs = 0.f;
#pragma unroll
            for (int mt = 0; mt < 4; mt++) {
                float p0 = __expf(acc[mt][0] - mnew);
                float p1 = __expf(acc[mt][1] - mnew);
                float p2 = __expf(acc[mt][2] - mnew);
                float p3 = __expf(acc[mt][3] - mnew);
                rs += (p0 + p1) + (p2 + p3);
                ushort4 pk; pk.x = f2bf(p0); pk.y = f2bf(p1); pk.z = f2bf(p2); pk.w = f2bf(p3);
                *(ushort4*)(pl + lm * 72 + mt * 16 + lq * 4) = pk;   // ds_write_b64
            }
            rs += __shfl_xor(rs, 16);
            rs += __shfl_xor(rs, 32);
            l_s = l_s * alpha + rs;

#pragma unroll
            for (int mt = 0; mt < 8; mt++)
#pragma unroll
                for (int r = 0; r < 4; r++) o[mt][r] *= alpha;

            // O^T += V^T · P^T : A=V^T[m=dim][k=key], B=P[n=q][k=key]
#pragma unroll
            for (int ks2 = 0; ks2 < 2; ks2++) {
                short8 bp = *(const short8*)(pl + lm * 72 + ks2 * 32 + lq * 8);
#pragma unroll
                for (int mt = 0; mt < 8; mt++) {
                    short8 av = *(const short8*)(Vl + (mt * 16 + lm) * 72 + ks2 * 32 + lq * 8);
                    o[mt] = __builtin_amdgcn_mfma_f32_16x16x32_bf16(av, bp, o[mt], 0, 0, 0);
                }
            }
        }
        // epilogue: O^T C-layout: col=q=lm, row=dim=mt*16+lq*4+r -> packed 8B stores
        float inv = 1.0f / l_s;
        u16* orow = out + (size_t)(b * S + qrow + lm) * 2048 + h * 128;
#pragma unroll
        for (int mt = 0; mt < 8; mt++) {
            ushort4 pk;
            pk.x = f2bf(o[mt][0] * inv);
            pk.y = f2bf(o[mt][1] * inv);
            pk.z = f2bf(o[mt][2] * inv);
            pk.w = f2bf(o[mt][3] * inv);
            *(ushort4*)(orow + mt * 16 + lq * 4) = pk;
        }
    }
}

extern "C" void kernel_launch(void* const* d_in, const int* in_sizes, int n_in,
                              void* d_out, int out_size, void* d_ws, size_t ws_size,
                              hipStream_t stream) {
    const int B = 2, S = 2048, D = 2048, H = 16;
    const int M = B * S;                       // 4096
    const float scale = 0.07216878364870323f;  // 1/sqrt(192), folded into Wq/Wq_rope
    const float* x    = (const float*)d_in[0];
    const float* Wq   = (const float*)d_in[1];
    const float* Wqr  = (const float*)d_in[2];
    const float* Wkvd = (const float*)d_in[3];
    const float* Wkvu = (const float*)d_in[4];
    const float* Wkr  = (const float*)d_in[5];
    const float* Wo   = (const float*)d_in[6];

    u16* p = (u16*)d_ws;
    u16* xb    = p; p += (size_t)M * D;
    u16* WqT   = p; p += (size_t)2048 * 2048;
    u16* WqrT  = p; p += (size_t)1024 * 2048;
    u16* WkvdT = p; p += (size_t)512 * 2048;
    u16* WkvuT = p; p += (size_t)4096 * 512;
    u16* WkrT  = p; p += (size_t)64 * 2048;
    u16* WoT   = p; p += (size_t)2048 * 2048;
    u16* q_c   = p; p += (size_t)M * 2048;
    u16* q_r   = p; p += (size_t)M * 1024;
    u16* c_kv  = p; p += (size_t)M * 512;
    u16* k_r   = p; p += (size_t)M * 64;
    u16* kv    = p; p += (size_t)M * 4096;
    u16* v_t   = p; p += (size_t)B * H * 128 * S;
    u16* attn  = p; p += (size_t)M * 2048;

    // 1) casts / transposes (Wq, Wq_rope pre-scaled by 1/sqrt(192))
    cast_f32_bf16<<<(M * D) / 4 / 256, 256, 0, stream>>>(x, xb, M * D);
    transpose_cast<<<dim3(32, 32), 256, 0, stream>>>(Wq,   WqT,   2048, 2048, scale);
    transpose_cast<<<dim3(32, 16), 256, 0, stream>>>(Wqr,  WqrT,  2048, 1024, scale);
    transpose_cast<<<dim3(32, 8),  256, 0, stream>>>(Wkvd, WkvdT, 2048, 512, 1.0f);
    transpose_cast<<<dim3(8, 64),  256, 0, stream>>>(Wkvu, WkvuT, 512, 4096, 1.0f);
    transpose_cast<<<dim3(32, 1),  256, 0, stream>>>(Wkr,  WkrT,  2048, 64, 1.0f);
    transpose_cast<<<dim3(32, 32), 256, 0, stream>>>(Wo,   WoT,   2048, 2048, 1.0f);

    // 2) projections
    gemm_bt<0><<<dim3(32, 16), 256, 0, stream>>>(xb, WqT,   q_c,  M, 2048, 2048);
    gemm_bt<0><<<dim3(32, 8),  256, 0, stream>>>(xb, WqrT,  q_r,  M, 1024, 2048);
    gemm_bt<0><<<dim3(32, 4),  256, 0, stream>>>(xb, WkvdT, c_kv, M, 512, 2048);
    gemm_bt<0><<<dim3(32, 1),  256, 0, stream>>>(xb, WkrT,  k_r,  M, 64, 2048);

    // 3) RoPE (in place; q_r is pre-scaled — rotation is linear, scale commutes)
    rope_kernel<<<(M * 16 * 32) / 256, 256, 0, stream>>>(q_r, M, 16, S - 1);
    rope_kernel<<<(M * 32) / 256, 256, 0, stream>>>(k_r, M, 1, S - 1);

    // 4) kv up-projection, V transpose
    gemm_bt<0><<<dim3(32, 32), 256, 0, stream>>>(c_kv, WkvuT, kv, M, 4096, 512);
    transpose_v<<<dim3(32, 2, 32), 256, 0, stream>>>(kv, v_t, S);

    // 5) attention (paired q-tiles for causal load balance)
    mla_attn<<<dim3(16, 32), 256, 0, stream>>>(q_c, q_r, kv, k_r, v_t, attn, S);

    // 6) output projection -> fp32 d_out
    gemm_bt<1><<<dim3(32, 16), 256, 0, stream>>>(attn, WoT, d_out, M, 2048, 2048);
}

// Round 6
// 429.626 us; speedup vs baseline: 2.4505x; 1.2327x over previous
//
#include <hip/hip_runtime.h>
#include <hip/hip_bf16.h>
#include <cstdint>
#include <cstddef>

typedef unsigned short u16;
typedef __attribute__((ext_vector_type(8))) short short8;   // 8 bf16 = 4 VGPRs (MFMA A/B frag)
typedef __attribute__((ext_vector_type(4))) float f32x4;    // MFMA C/D frag

__device__ __forceinline__ u16 f2bf(float f) {
    union { float f; uint32_t u; } v; v.f = f;
    uint32_t u = v.u;
    return (u16)((u + 0x7fffu + ((u >> 16) & 1u)) >> 16);   // RNE
}
__device__ __forceinline__ float bf2f(u16 u) {
    union { uint32_t u; float f; } v; v.u = ((uint32_t)u) << 16;
    return v.f;
}

// async global->LDS 16B copy (m97: global_load_lds_dwordx4).
// LDS dest is wave-uniform base + lane*16; global addr is per-lane.
__device__ __forceinline__ void async_cp16(const u16* g, u16* l) {
    __builtin_amdgcn_global_load_lds(
        (const __attribute__((address_space(1))) unsigned int*)g,
        (__attribute__((address_space(3))) unsigned int*)l, 16, 0, 0);
}

// ---------------- cast fp32 -> bf16 (vectorized) ----------------
__global__ __launch_bounds__(256) void cast_f32_bf16(const float* __restrict__ in,
                                                     u16* __restrict__ out, int n) {
    int i = (blockIdx.x * 256 + threadIdx.x) * 4;
    if (i >= n) return;
    float4 v = *(const float4*)(in + i);
    ushort4 r;
    r.x = f2bf(v.x); r.y = f2bf(v.y); r.z = f2bf(v.z); r.w = f2bf(v.w);
    *(ushort4*)(out + i) = r;
}

// ---------------- W (K,N) fp32 -> Wt (N,K) bf16 (optionally pre-scaled) ----------------
__global__ __launch_bounds__(256) void transpose_cast(const float* __restrict__ W,
                                                      u16* __restrict__ Wt, int K, int N,
                                                      float smul) {
    __shared__ u16 tile[64][72];
    int kt = blockIdx.x * 64, nt = blockIdx.y * 64;
    int t = threadIdx.x;
#pragma unroll
    for (int i = 0; i < 16; i++) {
        int idx = t + i * 256; int kl = idx >> 6, nl = idx & 63;
        tile[kl][nl] = f2bf(W[(size_t)(kt + kl) * N + nt + nl] * smul);
    }
    __syncthreads();
#pragma unroll
    for (int i = 0; i < 16; i++) {
        int idx = t + i * 256; int nl = idx >> 6, kl = idx & 63;
        Wt[(size_t)(nt + nl) * K + kt + kl] = tile[kl][nl];
    }
}

// ---------------- bf16 GEMM (m97 structure), compile-time shapes ----------------
// C(M,NDIM) = A(M,KDIM rows of lda) @ Bt(NDIM,KDIM)^T ; C row stride = ldc.
// 128x128 tile, BK=32, 4 waves 2x2, mfma 16x16x32, async global_load_lds staging.
template <int OUTF32, int KDIM, int NDIM>
__global__ __launch_bounds__(256) void gemm_bt(const u16* __restrict__ A, int lda,
                                               const u16* __restrict__ Bt,
                                               void* __restrict__ Cout, int ldc) {
    __shared__ __align__(16) u16 Al[128 * 32];   // 8 KB, rows of 32 elems (64 B), no pad
    __shared__ __align__(16) u16 Bl[128 * 32];
    int m0 = blockIdx.x * 128, n0 = blockIdx.y * 128;
    int t = threadIdx.x;
    int w = t >> 6, l = t & 63;
    int lm = l & 15, lq = l >> 4;
    int wm = (w >> 1) * 64, wn = (w & 1) * 64;
    f32x4 acc[4][4] = {};

    for (int k0 = 0; k0 < KDIM; k0 += 32) {
#pragma unroll
        for (int c = 0; c < 2; c++) {
            int chunk = w * 128 + c * 64 + l;          // per-lane chunk id
            int row = chunk >> 2, col8 = (chunk & 3) * 8;
            async_cp16(A + (size_t)(m0 + row) * lda + k0 + col8,
                       Al + (w * 128 + c * 64) * 8);   // wave-uniform LDS base
            int brow = n0 + row;
            if (NDIM % 128 != 0) { if (brow >= NDIM) brow = NDIM - 1; }  // partial-N clamp
            async_cp16(Bt + (size_t)brow * KDIM + k0 + col8,
                       Bl + (w * 128 + c * 64) * 8);
        }
        __syncthreads();
        short8 af[4], bfr[4];
#pragma unroll
        for (int mt = 0; mt < 4; mt++)
            af[mt] = *(const short8*)(Al + (wm + mt * 16 + lm) * 32 + lq * 8);
#pragma unroll
        for (int nt = 0; nt < 4; nt++)
            bfr[nt] = *(const short8*)(Bl + (wn + nt * 16 + lm) * 32 + lq * 8);
#pragma unroll
        for (int mt = 0; mt < 4; mt++)
#pragma unroll
            for (int nt = 0; nt < 4; nt++)
                acc[mt][nt] = __builtin_amdgcn_mfma_f32_16x16x32_bf16(af[mt], bfr[nt], acc[mt][nt], 0, 0, 0);
        __syncthreads();
    }
#pragma unroll
    for (int mt = 0; mt < 4; mt++) {
#pragma unroll
        for (int nt = 0; nt < 4; nt++) {
            int col = n0 + wn + nt * 16 + lm;
            if (col < NDIM) {
#pragma unroll
                for (int r = 0; r < 4; r++) {
                    int row = m0 + wm + mt * 16 + lq * 4 + r;
                    if (OUTF32) ((float*)Cout)[(size_t)row * ldc + col] = acc[mt][nt][r];
                    else        ((u16*)Cout)[(size_t)row * ldc + col] = f2bf(acc[mt][nt][r]);
                }
            }
        }
    }
}

// ---------------- RoPE in-place on (rows, nheads*64) bf16, row stride `stride` ----------------
__global__ __launch_bounds__(256) void rope_kernel(u16* __restrict__ x, int rows,
                                                   int nheads, int Smask, int stride) {
    int i = blockIdx.x * 256 + threadIdx.x;
    int total = rows * nheads * 32;
    if (i >= total) return;
    int j = i & 31;
    int h = (i >> 5) % nheads;
    int row = i / (32 * nheads);
    int pos = row & Smask;                       // pos = s (S power of two)
    float f = exp2f((float)j * -0.4152410118609828f);
    float ang = (float)pos * f;
    float c = cosf(ang), s = sinf(ang);
    u16* p = x + (size_t)row * stride + h * 64 + j;
    float x1 = bf2f(p[0]), x2 = bf2f(p[32]);
    p[0]  = f2bf(x1 * c - x2 * s);
    p[32] = f2bf(x2 * c + x1 * s);
}

// ---------------- V slice of kv -> v_t (B,H,128,S) bf16 ----------------
__global__ __launch_bounds__(256) void transpose_v(const u16* __restrict__ kv,
                                                   u16* __restrict__ vt, int S) {
    __shared__ u16 tile[64][72];
    int bh = blockIdx.z; int b = bh >> 4, h = bh & 15;
    int s0 = blockIdx.x * 64, d0 = blockIdx.y * 64;
    int t = threadIdx.x;
#pragma unroll
    for (int i = 0; i < 16; i++) {
        int idx = t + i * 256; int sl = idx >> 6, dl = idx & 63;
        tile[sl][dl] = kv[(size_t)(b * S + s0 + sl) * 4096 + 2048 + h * 128 + d0 + dl];
    }
    __syncthreads();
#pragma unroll
    for (int i = 0; i < 16; i++) {
        int idx = t + i * 256; int dl = idx >> 6, sl = idx & 63;
        vt[((size_t)(bh * 128 + d0 + dl)) * S + s0 + sl] = tile[sl][dl];
    }
}

// ---------------- Flash MLA attention v3 (unchanged structure; stride params) ----------------
// S^T = K·Q^T -> C: col=q, row=key. Each lane owns ONE q-row (2-shfl softmax).
// O^T = V^T·P^T -> C: col=q, row=dim; packed 8B stores. Q pre-scaled by 1/sqrt(192).
__global__ __launch_bounds__(256) void mla_attn(const u16* __restrict__ qc, int qcs,
                                                const u16* __restrict__ qr, int qrs,
                                                const u16* __restrict__ kvbuf,
                                                const u16* __restrict__ kr, int krs,
                                                const u16* __restrict__ vt,
                                                u16* __restrict__ out, int S) {
    __shared__ __align__(16) u16 Kl[64 * 200];       // 64 keys x 192 dims, stride 200
    __shared__ __align__(16) u16 Vl[128 * 72];       // 128 dims x 64 keys, stride 72
    __shared__ __align__(16) u16 Plds[4][16 * 72];   // per-wave P[q][key], stride 72
    int bh = blockIdx.y; int b = bh >> 4, h = bh & 15;
    int pair = blockIdx.x;
    int t = threadIdx.x, w = t >> 6, l = t & 63;
    int lm = l & 15, lq = l >> 4;

    short8 kreg[6], vreg[4];
    auto load_tile = [&](int kbase) {
#pragma unroll
        for (int c = 0; c < 6; c++) {                 // K: 64 rows x 24 chunks(16B)
            int idx = t + c * 256;
            int row = idx / 24, col = (idx % 24) * 8;
            const u16* src = (col < 128)
                ? kvbuf + (size_t)(b * S + kbase + row) * 4096 + h * 128 + col
                : kr + (size_t)(b * S + kbase + row) * krs + (col - 128);
            kreg[c] = *(const short8*)src;
        }
#pragma unroll
        for (int c = 0; c < 4; c++) {                 // V^T: 128 rows x 8 chunks(16B)
            int idx = t + c * 256;
            int row = idx >> 3, col = (idx & 7) * 8;
            vreg[c] = *(const short8*)(vt + ((size_t)bh * 128 + row) * S + kbase + col);
        }
    };

    for (int half = 0; half < 2; half++) {
        int qt = half ? (31 - pair) : pair;
        int qrow = qt * 64 + w * 16;                  // this wave's 16 q-rows
        int ntiles = qt + 1;

        // Q B-frags: B[n=q=lane&15][k=lq*8+j] (pre-scaled)
        short8 bq[6];
        {
            const u16* qc_row = qc + (size_t)(b * S + qrow + lm) * qcs + h * 128;
#pragma unroll
            for (int ks = 0; ks < 4; ks++) bq[ks] = *(const short8*)(qc_row + ks * 32 + lq * 8);
            const u16* qr_row = qr + (size_t)(b * S + qrow + lm) * qrs + h * 64;
#pragma unroll
            for (int ks = 0; ks < 2; ks++) bq[4 + ks] = *(const short8*)(qr_row + ks * 32 + lq * 8);
        }

        f32x4 o[8] = {};                              // O^T accs: 8 dim-tiles x (4 rows)
        float m_s = -INFINITY, l_s = 0.f;             // per-lane state for q-row (qrow+lm)

        load_tile(0);
        for (int kt = 0; kt < ntiles; kt++) {
            int kbase = kt * 64;
            __syncthreads();                          // prior iter's LDS reads done
#pragma unroll
            for (int c = 0; c < 6; c++) {
                int idx = t + c * 256;
                int row = idx / 24, col = (idx % 24) * 8;
                *(short8*)(Kl + row * 200 + col) = kreg[c];
            }
#pragma unroll
            for (int c = 0; c < 4; c++) {
                int idx = t + c * 256;
                int row = idx >> 3, col = (idx & 7) * 8;
                *(short8*)(Vl + row * 72 + col) = vreg[c];
            }
            __syncthreads();                          // staging visible to all waves
            if (kt + 1 < ntiles) load_tile(kbase + 64);   // overlaps compute below

            if (kbase > qrow + 15) continue;          // fully-masked for this wave

            // S^T: acc[mt][r] = S[q=qrow+lm][key=kbase+mt*16+lq*4+r]
            f32x4 acc[4] = {};
#pragma unroll
            for (int ks = 0; ks < 6; ks++) {
#pragma unroll
                for (int mt = 0; mt < 4; mt++) {
                    short8 ak = *(const short8*)(Kl + (mt * 16 + lm) * 200 + ks * 32 + lq * 8);
                    acc[mt] = __builtin_amdgcn_mfma_f32_16x16x32_bf16(ak, bq[ks], acc[mt], 0, 0, 0);
                }
            }
            if (kbase + 63 > qrow) {                  // diagonal tile: causal mask
                int qi = qrow + lm;
#pragma unroll
                for (int mt = 0; mt < 4; mt++)
#pragma unroll
                    for (int r = 0; r < 4; r++) {
                        int ki = kbase + mt * 16 + lq * 4 + r;
                        if (ki > qi) acc[mt][r] = -INFINITY;
                    }
            }
            // online softmax: intra-lane over 16 regs, then xor16/xor32 across lq replicas
            float mx = -INFINITY;
#pragma unroll
            for (int mt = 0; mt < 4; mt++)
#pragma unroll
                for (int r = 0; r < 4; r++) mx = fmaxf(mx, acc[mt][r]);
            mx = fmaxf(mx, __shfl_xor(mx, 16));
            mx = fmaxf(mx, __shfl_xor(mx, 32));
            float mnew = fmaxf(m_s, mx);
            float alpha = __expf(m_s - mnew);
            m_s = mnew;

            u16* pl = Plds[w];
            float rs = 0.f;
#pragma unroll
            for (int mt = 0; mt < 4; mt++) {
                float p0 = __expf(acc[mt][0] - mnew);
                float p1 = __expf(acc[mt][1] - mnew);
                float p2 = __expf(acc[mt][2] - mnew);
                float p3 = __expf(acc[mt][3] - mnew);
                rs += (p0 + p1) + (p2 + p3);
                ushort4 pk; pk.x = f2bf(p0); pk.y = f2bf(p1); pk.z = f2bf(p2); pk.w = f2bf(p3);
                *(ushort4*)(pl + lm * 72 + mt * 16 + lq * 4) = pk;   // ds_write_b64
            }
            rs += __shfl_xor(rs, 16);
            rs += __shfl_xor(rs, 32);
            l_s = l_s * alpha + rs;

#pragma unroll
            for (int mt = 0; mt < 8; mt++)
#pragma unroll
                for (int r = 0; r < 4; r++) o[mt][r] *= alpha;

            // O^T += V^T · P^T : A=V^T[m=dim][k=key], B=P[n=q][k=key]
#pragma unroll
            for (int ks2 = 0; ks2 < 2; ks2++) {
                short8 bp = *(const short8*)(pl + lm * 72 + ks2 * 32 + lq * 8);
#pragma unroll
                for (int mt = 0; mt < 8; mt++) {
                    short8 av = *(const short8*)(Vl + (mt * 16 + lm) * 72 + ks2 * 32 + lq * 8);
                    o[mt] = __builtin_amdgcn_mfma_f32_16x16x32_bf16(av, bp, o[mt], 0, 0, 0);
                }
            }
        }
        // epilogue: O^T C-layout: col=q=lm, row=dim=mt*16+lq*4+r -> packed 8B stores
        float inv = 1.0f / l_s;
        u16* orow = out + (size_t)(b * S + qrow + lm) * 2048 + h * 128;
#pragma unroll
        for (int mt = 0; mt < 8; mt++) {
            ushort4 pk;
            pk.x = f2bf(o[mt][0] * inv);
            pk.y = f2bf(o[mt][1] * inv);
            pk.z = f2bf(o[mt][2] * inv);
            pk.w = f2bf(o[mt][3] * inv);
            *(ushort4*)(orow + mt * 16 + lq * 4) = pk;
        }
    }
}

extern "C" void kernel_launch(void* const* d_in, const int* in_sizes, int n_in,
                              void* d_out, int out_size, void* d_ws, size_t ws_size,
                              hipStream_t stream) {
    const int B = 2, S = 2048, D = 2048, H = 16;
    const int M = B * S;                       // 4096
    const int NP = 3648;                       // merged proj cols: 2048+1024+512+64
    const int NPpad = 3712;                    // 29 tiles of 128
    const float scale = 0.07216878364870323f;  // 1/sqrt(192), folded into Wq/Wq_rope
    const float* x    = (const float*)d_in[0];
    const float* Wq   = (const float*)d_in[1];
    const float* Wqr  = (const float*)d_in[2];
    const float* Wkvd = (const float*)d_in[3];
    const float* Wkvu = (const float*)d_in[4];
    const float* Wkr  = (const float*)d_in[5];
    const float* Wo   = (const float*)d_in[6];

    u16* p = (u16*)d_ws;
    u16* xb     = p; p += (size_t)M * D;             // 16.8 MB
    u16* WprojT = p; p += (size_t)NPpad * 2048;      // rows: [Wq|Wqr|Wkvd|Wkr|pad]
    u16* WkvuT  = p; p += (size_t)4096 * 512;
    u16* WoT    = p; p += (size_t)2048 * 2048;
    u16* proj   = p; p += (size_t)M * NPpad;         // [q_c|q_r|c_kv|k_r] row-major
    u16* kv     = p; p += (size_t)M * 4096;
    u16* v_t    = p; p += (size_t)B * H * 128 * S;
    u16* attn   = p; p += (size_t)M * 2048;

    u16* q_c = proj;                 // cols 0..2047
    u16* q_r = proj + 2048;          // cols 2048..3071
    u16* ckv = proj + 3072;          // cols 3072..3583
    u16* k_r = proj + 3584;          // cols 3584..3647

    // 1) casts / transposes (Wq, Wq_rope pre-scaled by 1/sqrt(192))
    cast_f32_bf16<<<(M * D) / 4 / 256, 256, 0, stream>>>(x, xb, M * D);
    transpose_cast<<<dim3(32, 32), 256, 0, stream>>>(Wq,   WprojT,               2048, 2048, scale);
    transpose_cast<<<dim3(32, 16), 256, 0, stream>>>(Wqr,  WprojT + 2048 * 2048, 2048, 1024, scale);
    transpose_cast<<<dim3(32, 8),  256, 0, stream>>>(Wkvd, WprojT + 3072 * 2048, 2048, 512, 1.0f);
    transpose_cast<<<dim3(32, 1),  256, 0, stream>>>(Wkr,  WprojT + 3584 * 2048, 2048, 64, 1.0f);
    transpose_cast<<<dim3(8, 64),  256, 0, stream>>>(Wkvu, WkvuT, 512, 4096, 1.0f);
    transpose_cast<<<dim3(32, 32), 256, 0, stream>>>(Wo,   WoT,   2048, 2048, 1.0f);

    // 2) merged projection GEMM: proj = xb @ WprojT^T  (grid 32x29 = 928 blocks)
    gemm_bt<0, 2048, NP><<<dim3(32, 29), 256, 0, stream>>>(xb, 2048, WprojT, proj, NPpad);

    // 3) RoPE (in place on proj slices; q_r pre-scaled — rotation linear, scale commutes)
    rope_kernel<<<(M * 16 * 32) / 256, 256, 0, stream>>>(q_r, M, 16, S - 1, NPpad);
    rope_kernel<<<(M * 32) / 256, 256, 0, stream>>>(k_r, M, 1, S - 1, NPpad);

    // 4) kv up-projection (A = c_kv inside proj, lda = NPpad), V transpose
    gemm_bt<0, 512, 4096><<<dim3(32, 32), 256, 0, stream>>>(ckv, NPpad, WkvuT, kv, 4096);
    transpose_v<<<dim3(32, 2, 32), 256, 0, stream>>>(kv, v_t, S);

    // 5) attention (paired q-tiles for causal load balance)
    mla_attn<<<dim3(16, 32), 256, 0, stream>>>(q_c, NPpad, q_r, NPpad, kv, k_r, NPpad,
                                               v_t, attn, S);

    // 6) output projection -> fp32 d_out
    gemm_bt<1, 2048, 2048><<<dim3(32, 16), 256, 0, stream>>>(attn, 2048, WoT, d_out, 2048);
}

// Round 7
// 424.526 us; speedup vs baseline: 2.4800x; 1.0120x over previous
//
#include <hip/hip_runtime.h>
#include <hip/hip_bf16.h>
#include <cstdint>
#include <cstddef>

typedef unsigned short u16;
typedef __attribute__((ext_vector_type(8))) short short8;   // 8 bf16 = 4 VGPRs (MFMA A/B frag)
typedef __attribute__((ext_vector_type(4))) float f32x4;    // MFMA C/D frag

__device__ __forceinline__ u16 f2bf(float f) {
    union { float f; uint32_t u; } v; v.f = f;
    uint32_t u = v.u;
    return (u16)((u + 0x7fffu + ((u >> 16) & 1u)) >> 16);   // RNE
}
__device__ __forceinline__ float bf2f(u16 u) {
    union { uint32_t u; float f; } v; v.u = ((uint32_t)u) << 16;
    return v.f;
}

// async global->LDS 16B copy (m97: global_load_lds_dwordx4).
// LDS dest is wave-uniform base + lane*16; global addr is per-lane.
__device__ __forceinline__ void async_cp16(const u16* g, u16* l) {
    __builtin_amdgcn_global_load_lds(
        (const __attribute__((address_space(1))) unsigned int*)g,
        (__attribute__((address_space(3))) unsigned int*)l, 16, 0, 0);
}

// ---------------- cast fp32 -> bf16 (vectorized) ----------------
__global__ __launch_bounds__(256) void cast_f32_bf16(const float* __restrict__ in,
                                                     u16* __restrict__ out, int n) {
    int i = (blockIdx.x * 256 + threadIdx.x) * 4;
    if (i >= n) return;
    float4 v = *(const float4*)(in + i);
    ushort4 r;
    r.x = f2bf(v.x); r.y = f2bf(v.y); r.z = f2bf(v.z); r.w = f2bf(v.w);
    *(ushort4*)(out + i) = r;
}

// ---------------- W (K,N) fp32 -> Wt (N,K) bf16 (optionally pre-scaled) ----------------
__global__ __launch_bounds__(256) void transpose_cast(const float* __restrict__ W,
                                                      u16* __restrict__ Wt, int K, int N,
                                                      float smul) {
    __shared__ u16 tile[64][72];
    int kt = blockIdx.x * 64, nt = blockIdx.y * 64;
    int t = threadIdx.x;
#pragma unroll
    for (int i = 0; i < 16; i++) {
        int idx = t + i * 256; int kl = idx >> 6, nl = idx & 63;
        tile[kl][nl] = f2bf(W[(size_t)(kt + kl) * N + nt + nl] * smul);
    }
    __syncthreads();
#pragma unroll
    for (int i = 0; i < 16; i++) {
        int idx = t + i * 256; int nl = idx >> 6, kl = idx & 63;
        Wt[(size_t)(nt + nl) * K + kt + kl] = tile[kl][nl];
    }
}

// ---------------- bf16 GEMM (m97 structure), compile-time shapes ----------------
// C(M,NDIM) = A(M,KDIM rows of lda) @ Bt(NDIM,KDIM)^T ; C row stride = ldc.
// 128x128 tile, BK=32, 4 waves 2x2, mfma 16x16x32, async global_load_lds staging.
template <int OUTF32, int KDIM, int NDIM>
__global__ __launch_bounds__(256) void gemm_bt(const u16* __restrict__ A, int lda,
                                               const u16* __restrict__ Bt,
                                               void* __restrict__ Cout, int ldc) {
    __shared__ __align__(16) u16 Al[128 * 32];   // 8 KB, rows of 32 elems (64 B), no pad
    __shared__ __align__(16) u16 Bl[128 * 32];
    int m0 = blockIdx.x * 128, n0 = blockIdx.y * 128;
    int t = threadIdx.x;
    int w = t >> 6, l = t & 63;
    int lm = l & 15, lq = l >> 4;
    int wm = (w >> 1) * 64, wn = (w & 1) * 64;
    f32x4 acc[4][4] = {};

    for (int k0 = 0; k0 < KDIM; k0 += 32) {
#pragma unroll
        for (int c = 0; c < 2; c++) {
            int chunk = w * 128 + c * 64 + l;          // per-lane chunk id
            int row = chunk >> 2, col8 = (chunk & 3) * 8;
            async_cp16(A + (size_t)(m0 + row) * lda + k0 + col8,
                       Al + (w * 128 + c * 64) * 8);   // wave-uniform LDS base
            int brow = n0 + row;
            if (NDIM % 128 != 0) { if (brow >= NDIM) brow = NDIM - 1; }  // partial-N clamp
            async_cp16(Bt + (size_t)brow * KDIM + k0 + col8,
                       Bl + (w * 128 + c * 64) * 8);
        }
        __syncthreads();
        short8 af[4], bfr[4];
#pragma unroll
        for (int mt = 0; mt < 4; mt++)
            af[mt] = *(const short8*)(Al + (wm + mt * 16 + lm) * 32 + lq * 8);
#pragma unroll
        for (int nt = 0; nt < 4; nt++)
            bfr[nt] = *(const short8*)(Bl + (wn + nt * 16 + lm) * 32 + lq * 8);
#pragma unroll
        for (int mt = 0; mt < 4; mt++)
#pragma unroll
            for (int nt = 0; nt < 4; nt++)
                acc[mt][nt] = __builtin_amdgcn_mfma_f32_16x16x32_bf16(af[mt], bfr[nt], acc[mt][nt], 0, 0, 0);
        __syncthreads();
    }
#pragma unroll
    for (int mt = 0; mt < 4; mt++) {
#pragma unroll
        for (int nt = 0; nt < 4; nt++) {
            int col = n0 + wn + nt * 16 + lm;
            if (col < NDIM) {
#pragma unroll
                for (int r = 0; r < 4; r++) {
                    int row = m0 + wm + mt * 16 + lq * 4 + r;
                    if (OUTF32) ((float*)Cout)[(size_t)row * ldc + col] = acc[mt][nt][r];
                    else        ((u16*)Cout)[(size_t)row * ldc + col] = f2bf(acc[mt][nt][r]);
                }
            }
        }
    }
}

// ---------------- RoPE in-place on (rows, nheads*64) bf16, row stride `stride` ----------------
__global__ __launch_bounds__(256) void rope_kernel(u16* __restrict__ x, int rows,
                                                   int nheads, int Smask, int stride) {
    int i = blockIdx.x * 256 + threadIdx.x;
    int total = rows * nheads * 32;
    if (i >= total) return;
    int j = i & 31;
    int h = (i >> 5) % nheads;
    int row = i / (32 * nheads);
    int pos = row & Smask;                       // pos = s (S power of two)
    float f = exp2f((float)j * -0.4152410118609828f);
    float ang = (float)pos * f;
    float c = cosf(ang), s = sinf(ang);
    u16* p = x + (size_t)row * stride + h * 64 + j;
    float x1 = bf2f(p[0]), x2 = bf2f(p[32]);
    p[0]  = f2bf(x1 * c - x2 * s);
    p[32] = f2bf(x2 * c + x1 * s);
}

// ---------------- V slice of kv -> v_t (B,H,128,S) bf16 ----------------
__global__ __launch_bounds__(256) void transpose_v(const u16* __restrict__ kv,
                                                   u16* __restrict__ vt, int S) {
    __shared__ u16 tile[64][72];
    int bh = blockIdx.z; int b = bh >> 4, h = bh & 15;
    int s0 = blockIdx.x * 64, d0 = blockIdx.y * 64;
    int t = threadIdx.x;
#pragma unroll
    for (int i = 0; i < 16; i++) {
        int idx = t + i * 256; int sl = idx >> 6, dl = idx & 63;
        tile[sl][dl] = kv[(size_t)(b * S + s0 + sl) * 4096 + 2048 + h * 128 + d0 + dl];
    }
    __syncthreads();
#pragma unroll
    for (int i = 0; i < 16; i++) {
        int idx = t + i * 256; int dl = idx >> 6, sl = idx & 63;
        vt[((size_t)(bh * 128 + d0 + dl)) * S + s0 + sl] = tile[sl][dl];
    }
}

// ---------------- Flash MLA attention v4: XCD-pinned (b,h) groups ----------------
// grid (bh=32, pair=16): linear block id = bh + 32*pair ≡ bh (mod 8) -> all 16
// pair-blocks of one (b,h) land on ONE XCD (round-robin dispatch), so the ~2.6 MB
// K/V working set of that head stays in that XCD's 4 MB L2 instead of being
// refetched from HBM by all 8 XCDs (round-6 counters: FETCH 268 MB vs ~90 ideal).
// S^T = K·Q^T -> C: col=q, row=key. Each lane owns ONE q-row (2-shfl softmax).
// O^T = V^T·P^T -> C: col=q, row=dim; packed 8B stores. Q pre-scaled by 1/sqrt(192).
__global__ __launch_bounds__(256) void mla_attn(const u16* __restrict__ qc, int qcs,
                                                const u16* __restrict__ qr, int qrs,
                                                const u16* __restrict__ kvbuf,
                                                const u16* __restrict__ kr, int krs,
                                                const u16* __restrict__ vt,
                                                u16* __restrict__ out, int S) {
    __shared__ __align__(16) u16 Kl[64 * 200];       // 64 keys x 192 dims, stride 200
    __shared__ __align__(16) u16 Vl[128 * 72];       // 128 dims x 64 keys, stride 72
    __shared__ __align__(16) u16 Plds[4][16 * 72];   // per-wave P[q][key], stride 72
    int bh = blockIdx.x; int b = bh >> 4, h = bh & 15;   // XCD-pinning swizzle
    int pair = blockIdx.y;
    int t = threadIdx.x, w = t >> 6, l = t & 63;
    int lm = l & 15, lq = l >> 4;

    short8 kreg[6], vreg[4];
    auto load_tile = [&](int kbase) {
#pragma unroll
        for (int c = 0; c < 6; c++) {                 // K: 64 rows x 24 chunks(16B)
            int idx = t + c * 256;
            int row = idx / 24, col = (idx % 24) * 8;
            const u16* src = (col < 128)
                ? kvbuf + (size_t)(b * S + kbase + row) * 4096 + h * 128 + col
                : kr + (size_t)(b * S + kbase + row) * krs + (col - 128);
            kreg[c] = *(const short8*)src;
        }
#pragma unroll
        for (int c = 0; c < 4; c++) {                 // V^T: 128 rows x 8 chunks(16B)
            int idx = t + c * 256;
            int row = idx >> 3, col = (idx & 7) * 8;
            vreg[c] = *(const short8*)(vt + ((size_t)bh * 128 + row) * S + kbase + col);
        }
    };

    for (int half = 0; half < 2; half++) {
        int qt = half ? (31 - pair) : pair;
        int qrow = qt * 64 + w * 16;                  // this wave's 16 q-rows
        int ntiles = qt + 1;

        // Q B-frags: B[n=q=lane&15][k=lq*8+j] (pre-scaled)
        short8 bq[6];
        {
            const u16* qc_row = qc + (size_t)(b * S + qrow + lm) * qcs + h * 128;
#pragma unroll
            for (int ks = 0; ks < 4; ks++) bq[ks] = *(const short8*)(qc_row + ks * 32 + lq * 8);
            const u16* qr_row = qr + (size_t)(b * S + qrow + lm) * qrs + h * 64;
#pragma unroll
            for (int ks = 0; ks < 2; ks++) bq[4 + ks] = *(const short8*)(qr_row + ks * 32 + lq * 8);
        }

        f32x4 o[8] = {};                              // O^T accs: 8 dim-tiles x (4 rows)
        float m_s = -INFINITY, l_s = 0.f;             // per-lane state for q-row (qrow+lm)

        load_tile(0);
        for (int kt = 0; kt < ntiles; kt++) {
            int kbase = kt * 64;
            __syncthreads();                          // prior iter's LDS reads done
#pragma unroll
            for (int c = 0; c < 6; c++) {
                int idx = t + c * 256;
                int row = idx / 24, col = (idx % 24) * 8;
                *(short8*)(Kl + row * 200 + col) = kreg[c];
            }
#pragma unroll
            for (int c = 0; c < 4; c++) {
                int idx = t + c * 256;
                int row = idx >> 3, col = (idx & 7) * 8;
                *(short8*)(Vl + row * 72 + col) = vreg[c];
            }
            __syncthreads();                          // staging visible to all waves
            if (kt + 1 < ntiles) load_tile(kbase + 64);   // overlaps compute below

            if (kbase > qrow + 15) continue;          // fully-masked for this wave

            // S^T: acc[mt][r] = S[q=qrow+lm][key=kbase+mt*16+lq*4+r]
            f32x4 acc[4] = {};
#pragma unroll
            for (int ks = 0; ks < 6; ks++) {
#pragma unroll
                for (int mt = 0; mt < 4; mt++) {
                    short8 ak = *(const short8*)(Kl + (mt * 16 + lm) * 200 + ks * 32 + lq * 8);
                    acc[mt] = __builtin_amdgcn_mfma_f32_16x16x32_bf16(ak, bq[ks], acc[mt], 0, 0, 0);
                }
            }
            if (kbase + 63 > qrow) {                  // diagonal tile: causal mask
                int qi = qrow + lm;
#pragma unroll
                for (int mt = 0; mt < 4; mt++)
#pragma unroll
                    for (int r = 0; r < 4; r++) {
                        int ki = kbase + mt * 16 + lq * 4 + r;
                        if (ki > qi) acc[mt][r] = -INFINITY;
                    }
            }
            // online softmax: intra-lane over 16 regs, then xor16/xor32 across lq replicas
            float mx = -INFINITY;
#pragma unroll
            for (int mt = 0; mt < 4; mt++)
#pragma unroll
                for (int r = 0; r < 4; r++) mx = fmaxf(mx, acc[mt][r]);
            mx = fmaxf(mx, __shfl_xor(mx, 16));
            mx = fmaxf(mx, __shfl_xor(mx, 32));
            float mnew = fmaxf(m_s, mx);
            float alpha = __expf(m_s - mnew);
            m_s = mnew;

            u16* pl = Plds[w];
            float rs = 0.f;
#pragma unroll
            for (int mt = 0; mt < 4; mt++) {
                float p0 = __expf(acc[mt][0] - mnew);
                float p1 = __expf(acc[mt][1] - mnew);
                float p2 = __expf(acc[mt][2] - mnew);
                float p3 = __expf(acc[mt][3] - mnew);
                rs += (p0 + p1) + (p2 + p3);
                ushort4 pk; pk.x = f2bf(p0); pk.y = f2bf(p1); pk.z = f2bf(p2); pk.w = f2bf(p3);
                *(ushort4*)(pl + lm * 72 + mt * 16 + lq * 4) = pk;   // ds_write_b64
            }
            rs += __shfl_xor(rs, 16);
            rs += __shfl_xor(rs, 32);
            l_s = l_s * alpha + rs;

#pragma unroll
            for (int mt = 0; mt < 8; mt++)
#pragma unroll
                for (int r = 0; r < 4; r++) o[mt][r] *= alpha;

            // O^T += V^T · P^T : A=V^T[m=dim][k=key], B=P[n=q][k=key]
#pragma unroll
            for (int ks2 = 0; ks2 < 2; ks2++) {
                short8 bp = *(const short8*)(pl + lm * 72 + ks2 * 32 + lq * 8);
#pragma unroll
                for (int mt = 0; mt < 8; mt++) {
                    short8 av = *(const short8*)(Vl + (mt * 16 + lm) * 72 + ks2 * 32 + lq * 8);
                    o[mt] = __builtin_amdgcn_mfma_f32_16x16x32_bf16(av, bp, o[mt], 0, 0, 0);
                }
            }
        }
        // epilogue: O^T C-layout: col=q=lm, row=dim=mt*16+lq*4+r -> packed 8B stores
        float inv = 1.0f / l_s;
        u16* orow = out + (size_t)(b * S + qrow + lm) * 2048 + h * 128;
#pragma unroll
        for (int mt = 0; mt < 8; mt++) {
            ushort4 pk;
            pk.x = f2bf(o[mt][0] * inv);
            pk.y = f2bf(o[mt][1] * inv);
            pk.z = f2bf(o[mt][2] * inv);
            pk.w = f2bf(o[mt][3] * inv);
            *(ushort4*)(orow + mt * 16 + lq * 4) = pk;
        }
    }
}

extern "C" void kernel_launch(void* const* d_in, const int* in_sizes, int n_in,
                              void* d_out, int out_size, void* d_ws, size_t ws_size,
                              hipStream_t stream) {
    const int B = 2, S = 2048, D = 2048, H = 16;
    const int M = B * S;                       // 4096
    const int NP = 3648;                       // merged proj cols: 2048+1024+512+64
    const int NPpad = 3712;                    // 29 tiles of 128
    const float scale = 0.07216878364870323f;  // 1/sqrt(192), folded into Wq/Wq_rope
    const float* x    = (const float*)d_in[0];
    const float* Wq   = (const float*)d_in[1];
    const float* Wqr  = (const float*)d_in[2];
    const float* Wkvd = (const float*)d_in[3];
    const float* Wkvu = (const float*)d_in[4];
    const float* Wkr  = (const float*)d_in[5];
    const float* Wo   = (const float*)d_in[6];

    u16* p = (u16*)d_ws;
    u16* xb     = p; p += (size_t)M * D;             // 16.8 MB
    u16* WprojT = p; p += (size_t)NPpad * 2048;      // rows: [Wq|Wqr|Wkvd|Wkr|pad]
    u16* WkvuT  = p; p += (size_t)4096 * 512;
    u16* WoT    = p; p += (size_t)2048 * 2048;
    u16* proj   = p; p += (size_t)M * NPpad;         // [q_c|q_r|c_kv|k_r] row-major
    u16* kv     = p; p += (size_t)M * 4096;
    u16* v_t    = p; p += (size_t)B * H * 128 * S;
    u16* attn   = p; p += (size_t)M * 2048;

    u16* q_c = proj;                 // cols 0..2047
    u16* q_r = proj + 2048;          // cols 2048..3071
    u16* ckv = proj + 3072;          // cols 3072..3583
    u16* k_r = proj + 3584;          // cols 3584..3647

    // 1) casts / transposes (Wq, Wq_rope pre-scaled by 1/sqrt(192))
    cast_f32_bf16<<<(M * D) / 4 / 256, 256, 0, stream>>>(x, xb, M * D);
    transpose_cast<<<dim3(32, 32), 256, 0, stream>>>(Wq,   WprojT,               2048, 2048, scale);
    transpose_cast<<<dim3(32, 16), 256, 0, stream>>>(Wqr,  WprojT + 2048 * 2048, 2048, 1024, scale);
    transpose_cast<<<dim3(32, 8),  256, 0, stream>>>(Wkvd, WprojT + 3072 * 2048, 2048, 512, 1.0f);
    transpose_cast<<<dim3(32, 1),  256, 0, stream>>>(Wkr,  WprojT + 3584 * 2048, 2048, 64, 1.0f);
    transpose_cast<<<dim3(8, 64),  256, 0, stream>>>(Wkvu, WkvuT, 512, 4096, 1.0f);
    transpose_cast<<<dim3(32, 32), 256, 0, stream>>>(Wo,   WoT,   2048, 2048, 1.0f);

    // 2) merged projection GEMM: proj = xb @ WprojT^T  (grid 32x29 = 928 blocks)
    gemm_bt<0, 2048, NP><<<dim3(32, 29), 256, 0, stream>>>(xb, 2048, WprojT, proj, NPpad);

    // 3) RoPE (in place on proj slices; q_r pre-scaled — rotation linear, scale commutes)
    rope_kernel<<<(M * 16 * 32) / 256, 256, 0, stream>>>(q_r, M, 16, S - 1, NPpad);
    rope_kernel<<<(M * 32) / 256, 256, 0, stream>>>(k_r, M, 1, S - 1, NPpad);

    // 4) kv up-projection (A = c_kv inside proj, lda = NPpad), V transpose
    gemm_bt<0, 512, 4096><<<dim3(32, 32), 256, 0, stream>>>(ckv, NPpad, WkvuT, kv, 4096);
    transpose_v<<<dim3(32, 2, 32), 256, 0, stream>>>(kv, v_t, S);

    // 5) attention — grid (bh, pair): pins each head's blocks to one XCD's L2
    mla_attn<<<dim3(32, 16), 256, 0, stream>>>(q_c, NPpad, q_r, NPpad, kv, k_r, NPpad,
                                               v_t, attn, S);

    // 6) output projection -> fp32 d_out
    gemm_bt<1, 2048, 2048><<<dim3(32, 16), 256, 0, stream>>>(attn, 2048, WoT, d_out, 2048);
}